// Round 4
// baseline (23391.858 us; speedup 1.0000x reference)
//
#include <hip/hip_runtime.h>
#include <math.h>

#define B_  32
#define S_  256
#define T_  400
#define M_  80
#define D_  512
#define H_  8
#define DH  64
#define BT  (B_*T_)    // 12800
#define BS  (B_*S_)    // 8192
#define G4  (4*D_)     // 2048
#define DM  (D_+M_)    // 592
#define TC_ 50         // time-chunk for xg

// ---------------------------------------------------------------- gate bias sums
__global__ __launch_bounds__(256) void k_prep(
    const float* __restrict__ bih0, const float* __restrict__ bhh0,
    const float* __restrict__ bih1, const float* __restrict__ bhh1,
    float* __restrict__ bsum0, float* __restrict__ bsum1)
{
    int i = blockIdx.x * 256 + threadIdx.x;
    if (i < G4) {
        bsum0[i] = bih0[i] + bhh0[i];
        bsum1[i] = bih1[i] + bhh1[i];
    }
}

// ---------------------------------------------------------------- Weff = W_in@Wq, beff = b_in@Wq + bq
__global__ __launch_bounds__(256) void k_weff(
    const float* __restrict__ W_in, const float* __restrict__ Wq,
    const float* __restrict__ b_in, const float* __restrict__ bq,
    float* __restrict__ Weff, float* __restrict__ beff)
{
    int idx = blockIdx.x * 256 + threadIdx.x;
    if (idx < M_ * D_) {
        int m = idx / D_, d = idx - m * D_;
        float acc = 0.f;
        for (int j = 0; j < D_; ++j)
            acc += W_in[(size_t)m * D_ + j] * Wq[(size_t)j * D_ + d];
        Weff[idx] = acc;
    }
    if (idx < D_) {
        float acc = bq[idx];
        for (int j = 0; j < D_; ++j)
            acc += b_in[j] * Wq[(size_t)j * D_ + idx];
        beff[idx] = acc;
    }
}

// ---------------------------------------------------------------- generic GEMM (fp32)
// C[M,N] = A[M,K] @ op(B) + bias ; 64x64 tile, BK=16, 256 thr, 4x4/thread.
__global__ __launch_bounds__(256) void k_gemm(
    const float* __restrict__ A, int lda,
    const float* __restrict__ Bm, int ldb, int transB,
    float* __restrict__ C, int ldc,
    const float* __restrict__ bias,
    int M, int N, int K)
{
    __shared__ float As[16][68];
    __shared__ float Bs[16][68];
    int m0 = blockIdx.x * 64, n0 = blockIdx.y * 64;
    int tid = threadIdx.x;
    int tm = (tid & 15) * 4, tn = (tid >> 4) * 4;
    float acc[4][4] = {};

    for (int k0 = 0; k0 < K; k0 += 16) {
        {
            int f = tid * 4;
            int mm = f >> 4, kk = f & 15;
            bool mok = (m0 + mm) < M;
            const float* ap = A + (size_t)(m0 + mm) * lda + (k0 + kk);
            #pragma unroll
            for (int i = 0; i < 4; ++i) {
                float v = 0.f;
                if (mok && (k0 + kk + i) < K) v = ap[i];
                As[kk + i][mm] = v;
            }
        }
        if (!transB) {
            int f = tid * 4;
            int kk = f >> 6, nn = f & 63;
            bool kok = (k0 + kk) < K;
            const float* bp = Bm + (size_t)(k0 + kk) * ldb + (n0 + nn);
            #pragma unroll
            for (int i = 0; i < 4; ++i) {
                float v = 0.f;
                if (kok && (n0 + nn + i) < N) v = bp[i];
                Bs[kk][nn + i] = v;
            }
        } else {
            int f = tid * 4;
            int nn = f >> 4, kk = f & 15;
            bool nok = (n0 + nn) < N;
            const float* bp = Bm + (size_t)(n0 + nn) * ldb + (k0 + kk);
            #pragma unroll
            for (int i = 0; i < 4; ++i) {
                float v = 0.f;
                if (nok && (k0 + kk + i) < K) v = bp[i];
                Bs[kk + i][nn] = v;
            }
        }
        __syncthreads();
        #pragma unroll
        for (int kk = 0; kk < 16; ++kk) {
            float4 av = *(const float4*)&As[kk][tm];
            float4 bv = *(const float4*)&Bs[kk][tn];
            float a[4] = {av.x, av.y, av.z, av.w};
            float b[4] = {bv.x, bv.y, bv.z, bv.w};
            #pragma unroll
            for (int i = 0; i < 4; ++i)
                #pragma unroll
                for (int j = 0; j < 4; ++j)
                    acc[i][j] += a[i] * b[j];
        }
        __syncthreads();
    }
    #pragma unroll
    for (int i = 0; i < 4; ++i) {
        int m = m0 + tm + i;
        if (m >= M) continue;
        #pragma unroll
        for (int j = 0; j < 4; ++j) {
            int n = n0 + tn + j;
            if (n >= N) continue;
            float v = acc[i][j];
            if (bias) v += bias[n];
            C[(size_t)m * ldc + n] = v;
        }
    }
}

// ---------------------------------------------------------------- chunked xg GEMM
// logical row m (0..B*TC-1) -> (bb=m/TC, t=t0+m%TC). A row = [Abase[bb*T+t, 0:512] | dec_in(bb,t)]
// dec_in appended iff mel != nullptr (K=592), else K=512. B is [2048, K] row-major (trans).
// C[m, n] (ldc=2048) = row . B[n,:] + bias[n]
__global__ __launch_bounds__(256) void k_gemm_rows(
    const float* __restrict__ A, int t0,
    const float* __restrict__ mel,
    const float* __restrict__ Bm,
    float* __restrict__ C, const float* __restrict__ bias,
    int K)
{
    __shared__ float As[16][68];
    __shared__ float Bs[16][68];
    int m0 = blockIdx.x * 64, n0 = blockIdx.y * 64;
    int tid = threadIdx.x;
    int tm = (tid & 15) * 4, tn = (tid >> 4) * 4;
    float acc[4][4] = {};

    int fA = tid * 4;
    int mmA = fA >> 4, kkA = fA & 15;
    int m = m0 + mmA;
    int bb = m / TC_;
    int t = t0 + (m - bb * TC_);
    const float* Arow = A + (size_t)(bb * T_ + t) * D_;
    const float* Mrow = (mel != nullptr && t > 0) ? mel + (size_t)(bb * T_ + t - 1) * M_ : nullptr;

    for (int k0 = 0; k0 < K; k0 += 16) {
        #pragma unroll
        for (int i = 0; i < 4; ++i) {
            int k = k0 + kkA + i;
            float v;
            if (k < D_) v = Arow[k];
            else v = Mrow ? Mrow[k - D_] : 0.f;
            As[kkA + i][mmA] = v;
        }
        {
            int f = tid * 4;
            int nn = f >> 4, kk = f & 15;
            const float* bp = Bm + (size_t)(n0 + nn) * K + (k0 + kk);
            #pragma unroll
            for (int i = 0; i < 4; ++i) {
                float v = ((k0 + kk + i) < K) ? bp[i] : 0.f;
                Bs[kk + i][nn] = v;
            }
        }
        __syncthreads();
        #pragma unroll
        for (int kk = 0; kk < 16; ++kk) {
            float4 av = *(const float4*)&As[kk][tm];
            float4 bv = *(const float4*)&Bs[kk][tn];
            float a[4] = {av.x, av.y, av.z, av.w};
            float b[4] = {bv.x, bv.y, bv.z, bv.w};
            #pragma unroll
            for (int i = 0; i < 4; ++i)
                #pragma unroll
                for (int j = 0; j < 4; ++j)
                    acc[i][j] += a[i] * b[j];
        }
        __syncthreads();
    }
    #pragma unroll
    for (int i = 0; i < 4; ++i) {
        int mo = m0 + tm + i;
        #pragma unroll
        for (int j = 0; j < 4; ++j) {
            int n = n0 + tn + j;
            C[(size_t)mo * G4 + n] = acc[i][j] + bias[n];
        }
    }
}

// ---------------------------------------------------------------- conv-GEMM (im2col fused into A staging)
__global__ __launch_bounds__(256) void k_gemm_conv(
    const float* __restrict__ src, int C,
    const float* __restrict__ Bm,
    float* __restrict__ Cout, int ldc,
    const float* __restrict__ bias,
    int M, int N, int K)
{
    __shared__ float As[16][68];
    __shared__ float Bs[16][68];
    int m0 = blockIdx.x * 64, n0 = blockIdx.y * 64;
    int tid = threadIdx.x;
    int tm = (tid & 15) * 4, tn = (tid >> 4) * 4;
    float acc[4][4] = {};

    int fA = tid * 4;
    int mmA = fA >> 4, kkA = fA & 15;
    int btA = m0 + mmA;
    int bA = btA / T_, tA = btA - bA * T_;

    for (int k0 = 0; k0 < K; k0 += 16) {
        #pragma unroll
        for (int i = 0; i < 4; ++i) {
            int ka = k0 + kkA + i;
            int c = ka / 5;
            int k = ka - c * 5;
            int tt = tA + k - 2;
            float v = 0.f;
            if (tt >= 0 && tt < T_) v = src[(size_t)(bA * T_ + tt) * C + c];
            As[kkA + i][mmA] = v;
        }
        {
            int f = tid * 4;
            int nn = f >> 4, kk = f & 15;
            bool nok = (n0 + nn) < N;
            const float* bp = Bm + (size_t)(n0 + nn) * K + (k0 + kk);
            #pragma unroll
            for (int i = 0; i < 4; ++i) {
                float v = 0.f;
                if (nok) v = bp[i];
                Bs[kk + i][nn] = v;
            }
        }
        __syncthreads();
        #pragma unroll
        for (int kk = 0; kk < 16; ++kk) {
            float4 av = *(const float4*)&As[kk][tm];
            float4 bv = *(const float4*)&Bs[kk][tn];
            float a[4] = {av.x, av.y, av.z, av.w};
            float b[4] = {bv.x, bv.y, bv.z, bv.w};
            #pragma unroll
            for (int i = 0; i < 4; ++i)
                #pragma unroll
                for (int j = 0; j < 4; ++j)
                    acc[i][j] += a[i] * b[j];
        }
        __syncthreads();
    }
    #pragma unroll
    for (int i = 0; i < 4; ++i) {
        int m = m0 + tm + i;
        if (m >= M) continue;
        #pragma unroll
        for (int j = 0; j < 4; ++j) {
            int n = n0 + tn + j;
            if (n >= N) continue;
            Cout[(size_t)m * ldc + n] = acc[i][j] + bias[n];
        }
    }
}

// ---------------------------------------------------------------- attention, q computed on the fly
// one wave per (b,h,t): q = dec_in(b,t) @ Weff + beff ; 256 scores -> softmax -> ctx[64]
__global__ __launch_bounds__(256) void k_attn(
    const float* __restrict__ mel,
    const float* __restrict__ Weff, const float* __restrict__ beff,
    const float* __restrict__ Kb, const float* __restrict__ Vb,
    float* __restrict__ ctx)
{
    __shared__ float mrow[4][80];
    __shared__ float qs[4][64];
    __shared__ float ps[4][256];
    int w = threadIdx.x >> 6, lane = threadIdx.x & 63;
    int row = blockIdx.x * 4 + w;
    int t = row % T_; int bh = row / T_;
    int h = bh % H_;  int b = bh / H_;

    {
        float v = 0.f;
        if (t > 0) v = mel[(size_t)(b * T_ + (t - 1)) * M_ + lane];
        mrow[w][lane] = v;
        if (lane < 16) {
            float v2 = 0.f;
            if (t > 0) v2 = mel[(size_t)(b * T_ + (t - 1)) * M_ + 64 + lane];
            mrow[w][64 + lane] = v2;
        }
    }
    __syncthreads();
    {
        int d = h * DH + lane;
        float q = beff[d];
        #pragma unroll 8
        for (int m = 0; m < M_; ++m) q += mrow[w][m] * Weff[(size_t)m * D_ + d];
        qs[w][lane] = q;
    }
    __syncthreads();

    const float* Kbase = Kb + (size_t)(b * S_) * D_ + h * DH;
    float sc[4];
    #pragma unroll
    for (int i = 0; i < 4; ++i) {
        int s = lane + i * 64;
        const float4* kr = (const float4*)(Kbase + (size_t)s * D_);
        float acc = 0.f;
        #pragma unroll
        for (int c4 = 0; c4 < 16; ++c4) {
            float4 kv = kr[c4];
            acc += qs[w][c4 * 4 + 0] * kv.x + qs[w][c4 * 4 + 1] * kv.y
                 + qs[w][c4 * 4 + 2] * kv.z + qs[w][c4 * 4 + 3] * kv.w;
        }
        sc[i] = acc * 0.125f;   // 1/sqrt(64)
    }
    float mx = fmaxf(fmaxf(sc[0], sc[1]), fmaxf(sc[2], sc[3]));
    #pragma unroll
    for (int off = 32; off; off >>= 1) mx = fmaxf(mx, __shfl_xor(mx, off, 64));
    float sum = 0.f;
    #pragma unroll
    for (int i = 0; i < 4; ++i) { sc[i] = __expf(sc[i] - mx); sum += sc[i]; }
    #pragma unroll
    for (int off = 32; off; off >>= 1) sum += __shfl_xor(sum, off, 64);
    float inv = 1.f / sum;
    #pragma unroll
    for (int i = 0; i < 4; ++i) ps[w][lane + i * 64] = sc[i] * inv;
    __syncthreads();

    const float* Vbase = Vb + (size_t)(b * S_) * D_ + h * DH + lane;
    float acc = 0.f;
    for (int s = 0; s < S_; ++s) acc += ps[w][s] * Vbase[(size_t)s * D_];
    ctx[(size_t)(b * T_ + t) * D_ + h * DH + lane] = acc;
}

// ---------------------------------------------------------------- LSTM step (chunked xg, ping-pong h)
__global__ __launch_bounds__(256) void k_lstm_step(
    const float* __restrict__ xgc,        // [B*TC, 2048] chunk-local (biases pre-added)
    const float* __restrict__ Whh,        // [2048,512]
    float* __restrict__ hseq,             // [B,T,512]
    const float* __restrict__ hprev,      // [B,512]
    float* __restrict__ hnext,            // [B,512]
    float* __restrict__ cst,              // [B,512]
    int t, int tl)
{
    __shared__ float hs[2][512];
    __shared__ float gl[4][2][64];
    int tid = threadIdx.x;
    int dl = tid & 63, g = tid >> 6;
    int b0 = blockIdx.x * 2, d0 = blockIdx.y * 64;
    int d = d0 + dl;

    float acc0 = 0.f, acc1 = 0.f;
    if (t > 0) {
        for (int i = tid; i < 2 * D_; i += 256) {
            int bb = i >> 9, k = i & 511;
            hs[bb][k] = hprev[(size_t)(b0 + bb) * D_ + k];
        }
        __syncthreads();
        const float4* wr = (const float4*)(Whh + (size_t)(g * D_ + d) * D_);
        #pragma unroll 8
        for (int k4 = 0; k4 < 128; ++k4) {
            float4 wv = wr[k4];
            acc0 += wv.x * hs[0][k4 * 4 + 0] + wv.y * hs[0][k4 * 4 + 1]
                  + wv.z * hs[0][k4 * 4 + 2] + wv.w * hs[0][k4 * 4 + 3];
            acc1 += wv.x * hs[1][k4 * 4 + 0] + wv.y * hs[1][k4 * 4 + 1]
                  + wv.z * hs[1][k4 * 4 + 2] + wv.w * hs[1][k4 * 4 + 3];
        }
    }
    gl[g][0][dl] = acc0 + xgc[(size_t)(b0 * TC_ + tl) * G4 + g * D_ + d];
    gl[g][1][dl] = acc1 + xgc[(size_t)((b0 + 1) * TC_ + tl) * G4 + g * D_ + d];
    __syncthreads();
    if (tid < 128) {
        int bb = tid >> 6, dd = tid & 63;
        float iv = gl[0][bb][dd], fv = gl[1][bb][dd];
        float gv = gl[2][bb][dd], ov = gl[3][bb][dd];
        float si = 1.f / (1.f + __expf(-iv));
        float sf = 1.f / (1.f + __expf(-fv));
        float so = 1.f / (1.f + __expf(-ov));
        float tg = tanhf(gv);
        int b = b0 + bb;
        size_t ci = (size_t)b * D_ + d0 + dd;
        float cold = (t == 0) ? 0.f : cst[ci];
        float c = sf * cold + si * tg;
        float h = so * tanhf(c);
        cst[ci] = c;
        hnext[ci] = h;
        hseq[(size_t)(b * T_ + t) * D_ + d0 + dd] = h;
    }
}

// ---------------------------------------------------------------- BN stats (training mode)
__global__ __launch_bounds__(256) void k_stats(
    const float* __restrict__ x, int C,
    const float* __restrict__ gw, const float* __restrict__ bw,
    float* __restrict__ scale, float* __restrict__ shift)
{
    int c = blockIdx.x;
    float s = 0.f, ss = 0.f;
    for (int r = threadIdx.x; r < BT; r += 256) {
        float v = x[(size_t)r * C + c];
        s += v; ss += v * v;
    }
    __shared__ float rs[256], rq[256];
    rs[threadIdx.x] = s; rq[threadIdx.x] = ss;
    __syncthreads();
    for (int off = 128; off; off >>= 1) {
        if (threadIdx.x < off) {
            rs[threadIdx.x] += rs[threadIdx.x + off];
            rq[threadIdx.x] += rq[threadIdx.x + off];
        }
        __syncthreads();
    }
    if (threadIdx.x == 0) {
        float mean = rs[0] / (float)BT;
        float var  = rq[0] / (float)BT - mean * mean;
        float scv  = gw[c] * rsqrtf(var + 1e-5f);
        scale[c] = scv;
        shift[c] = bw[c] - mean * scv;
    }
}

__global__ __launch_bounds__(256) void k_bnact(
    float* __restrict__ x, int C,
    const float* __restrict__ scale, const float* __restrict__ shift)
{
    int idx = blockIdx.x * 256 + threadIdx.x;
    if (idx < BT * C) {
        int c = idx % C;
        x[idx] = tanhf(scale[c] * x[idx] + shift[c]);
    }
}

__global__ __launch_bounds__(256) void k_residual(
    const float* __restrict__ mel, float* __restrict__ out)
{
    int i = blockIdx.x * 256 + threadIdx.x;
    if (i < BT * M_) out[i] += mel[i];
}

// ================================================================ launch
extern "C" void kernel_launch(void* const* d_in, const int* in_sizes, int n_in,
                              void* d_out, int out_size, void* d_ws, size_t ws_size,
                              hipStream_t stream)
{
    const float* enc    = (const float*)d_in[0];
    const float* mel_t  = (const float*)d_in[1];
    const float* W_in   = (const float*)d_in[2];
    const float* b_in   = (const float*)d_in[3];
    const float* Wq     = (const float*)d_in[4];  const float* bq = (const float*)d_in[5];
    const float* Wk     = (const float*)d_in[6];  const float* bk = (const float*)d_in[7];
    const float* Wv     = (const float*)d_in[8];  const float* bv = (const float*)d_in[9];
    const float* Wo     = (const float*)d_in[10]; const float* bo = (const float*)d_in[11];
    const float* W_ih0  = (const float*)d_in[12]; const float* W_hh0 = (const float*)d_in[13];
    const float* b_ih0  = (const float*)d_in[14]; const float* b_hh0 = (const float*)d_in[15];
    const float* W_ih1  = (const float*)d_in[16]; const float* W_hh1 = (const float*)d_in[17];
    const float* b_ih1  = (const float*)d_in[18]; const float* b_hh1 = (const float*)d_in[19];
    const float* W_mel  = (const float*)d_in[20]; const float* b_mel = (const float*)d_in[21];
    const float* W_stop = (const float*)d_in[22]; const float* b_stop = (const float*)d_in[23];
    const float* pw0 = (const float*)d_in[24]; const float* pb0 = (const float*)d_in[25];
    const float* pw1 = (const float*)d_in[26]; const float* pb1 = (const float*)d_in[27];
    const float* pw2 = (const float*)d_in[28]; const float* pb2 = (const float*)d_in[29];
    const float* pw3 = (const float*)d_in[30]; const float* pb3 = (const float*)d_in[31];
    const float* pw4 = (const float*)d_in[32]; const float* pb4 = (const float*)d_in[33];
    const float* g0 = (const float*)d_in[34]; const float* be0 = (const float*)d_in[35];
    const float* g1 = (const float*)d_in[36]; const float* be1 = (const float*)d_in[37];
    const float* g2 = (const float*)d_in[38]; const float* be2 = (const float*)d_in[39];
    const float* g3 = (const float*)d_in[40]; const float* be3 = (const float*)d_in[41];

    char* p = (char*)d_ws;
    // ---- fp32 layout, peak ~63 MB. Lifetimes verified against launch order:
    //   Kb [0,16.78M) + Vb [16.78,33.55M)   : dead after k_attn
    //   ctx [33.55,59.77M)                  : dead after Wo GEMM
    //   ao  [0,26.21M)    (alias Kb+Vb)     : written after attn; dead after last L0 xg GEMM
    //   xgc [26.21,39.32M)(alias Vb tail+ctx head): written after Wo GEMM
    //   h1  [39.32,65.54M)(alias ctx tail)  : written by L0 steps; dead after last L1 xg GEMM
    //   h2  [0,26.21M)    (alias ao)        : written by L1 steps; dead after heads
    //   p_a [26.21,52.43M), p_b [0,26.21M)  : postnet ping-pong
    float* Kb  = (float*)(p + 0);
    float* Vb  = (float*)(p + 16777216);
    float* ctx = (float*)(p + 33554432);
    float* ao  = (float*)(p + 0);
    float* xgc = (float*)(p + 26214400);
    float* h1  = (float*)(p + 39321600);
    float* h2  = (float*)(p + 0);
    float* p_a = (float*)(p + 26214400);
    float* p_b = (float*)(p + 0);
    size_t off = 65536000;
    float* bsum0 = (float*)(p + off); off += 8192;
    float* bsum1 = (float*)(p + off); off += 8192;
    float* cbuf  = (float*)(p + off); off += 65536;
    float* hA    = (float*)(p + off); off += 65536;
    float* hB    = (float*)(p + off); off += 65536;
    float* sc0 = (float*)(p + off); off += 2048;
    float* sh0 = (float*)(p + off); off += 2048;
    float* sc1 = (float*)(p + off); off += 2048;
    float* sh1 = (float*)(p + off); off += 2048;
    float* sc2 = (float*)(p + off); off += 2048;
    float* sh2 = (float*)(p + off); off += 2048;
    float* sc3 = (float*)(p + off); off += 2048;
    float* sh3 = (float*)(p + off); off += 2048;
    float* beff = (float*)(p + off); off += 2048;
    float* Weff = (float*)(p + off); off += 163840;
    // end ~65.93 MB

    float* out_mel  = (float*)d_out;
    float* out_post = out_mel + (size_t)BT * M_;
    float* out_stop = out_post + (size_t)BT * M_;

    dim3 blk(256);
    auto GEMM = [&](const float* A, int lda, const float* Bm, int ldb, int tB,
                    float* C, int ldc, const float* bias, int M, int N, int K) {
        dim3 g((M + 63) / 64, (N + 63) / 64);
        k_gemm<<<g, blk, 0, stream>>>(A, lda, Bm, ldb, tB, C, ldc, bias, M, N, K);
    };
    auto CONV = [&](const float* src, int C, const float* W, float* Y, int ldc,
                    const float* bias, int N) {
        int K = C * 5;
        dim3 g(BT / 64, (N + 63) / 64);
        k_gemm_conv<<<g, blk, 0, stream>>>(src, C, W, Y, ldc, bias, BT, N, K);
    };

    k_prep<<<8, blk, 0, stream>>>(b_ih0, b_hh0, b_ih1, b_hh1, bsum0, bsum1);
    k_weff<<<160, blk, 0, stream>>>(W_in, Wq, b_in, bq, Weff, beff);

    GEMM(enc, D_, Wk, D_, 0, Kb, D_, bk, BS, D_, D_);
    GEMM(enc, D_, Wv, D_, 0, Vb, D_, bv, BS, D_, D_);

    k_attn<<<(B_ * H_ * T_) / 4, blk, 0, stream>>>(mel_t, Weff, beff, Kb, Vb, ctx);

    // attn_out = ctx @ Wo + bo   (dec_in appended virtually inside xg GEMM)
    GEMM(ctx, D_, Wo, D_, 0, ao, D_, bo, BT, D_, D_);

    dim3 lg(16, 8);
    dim3 cg(B_ * TC_ / 64, G4 / 64);   // 25 x 32
    float* hb[2] = {hA, hB};

    // LSTM layer 0 (time-chunked xg; A = ao with virtual mel concat, K=592)
    for (int c = 0; c < T_ / TC_; ++c) {
        k_gemm_rows<<<cg, blk, 0, stream>>>(ao, c * TC_, mel_t, W_ih0, xgc, bsum0, DM);
        for (int tl = 0; tl < TC_; ++tl) {
            int t = c * TC_ + tl;
            k_lstm_step<<<lg, blk, 0, stream>>>(xgc, W_hh0, h1, hb[t & 1], hb[(t + 1) & 1], cbuf, t, tl);
        }
    }
    // LSTM layer 1 (A = h1, K=512)
    for (int c = 0; c < T_ / TC_; ++c) {
        k_gemm_rows<<<cg, blk, 0, stream>>>(h1, c * TC_, nullptr, W_ih1, xgc, bsum1, D_);
        for (int tl = 0; tl < TC_; ++tl) {
            int t = c * TC_ + tl;
            k_lstm_step<<<lg, blk, 0, stream>>>(xgc, W_hh1, h2, hb[t & 1], hb[(t + 1) & 1], cbuf, t, tl);
        }
    }

    // heads
    GEMM(h2, D_, W_mel,  M_, 0, out_mel,  M_, b_mel,  BT, M_, D_);
    GEMM(h2, D_, W_stop, 1,  0, out_stop, 1,  b_stop, BT, 1,  D_);

    // postnet
    int gD = (BT * D_ + 255) / 256;

    CONV(out_mel, M_, pw0, p_a, D_, pb0, D_);
    k_stats<<<512, blk, 0, stream>>>(p_a, D_, g0, be0, sc0, sh0);
    k_bnact<<<gD, blk, 0, stream>>>(p_a, D_, sc0, sh0);

    CONV(p_a, D_, pw1, p_b, D_, pb1, D_);
    k_stats<<<512, blk, 0, stream>>>(p_b, D_, g1, be1, sc1, sh1);
    k_bnact<<<gD, blk, 0, stream>>>(p_b, D_, sc1, sh1);

    CONV(p_b, D_, pw2, p_a, D_, pb2, D_);
    k_stats<<<512, blk, 0, stream>>>(p_a, D_, g2, be2, sc2, sh2);
    k_bnact<<<gD, blk, 0, stream>>>(p_a, D_, sc2, sh2);

    CONV(p_a, D_, pw3, p_b, D_, pb3, D_);
    k_stats<<<512, blk, 0, stream>>>(p_b, D_, g3, be3, sc3, sh3);
    k_bnact<<<gD, blk, 0, stream>>>(p_b, D_, sc3, sh3);

    // final conv straight into out_post, then residual add in place
    CONV(p_b, D_, pw4, out_post, M_, pb4, M_);
    k_residual<<<4000, blk, 0, stream>>>(out_mel, out_post);
}

// Round 5
// 22399.684 us; speedup vs baseline: 1.0443x; 1.0443x over previous
//
#include <hip/hip_runtime.h>
#include <math.h>

#define B_  32
#define S_  256
#define T_  400
#define M_  80
#define D_  512
#define H_  8
#define DH  64
#define BT  (B_*T_)    // 12800
#define BS  (B_*S_)    // 8192
#define G4  (4*D_)     // 2048
#define DM  (D_+M_)    // 592
#define TC_ 50         // time-chunk for xg

typedef short s16x8 __attribute__((ext_vector_type(8)));
typedef float f32x4 __attribute__((ext_vector_type(4)));

__device__ __forceinline__ unsigned short f2bf(float f) {
    union { float f; unsigned u; } v; v.f = f;
    unsigned r = v.u + 0x7fffu + ((v.u >> 16) & 1u);
    return (unsigned short)(r >> 16);
}

// ---------------------------------------------------------------- gate bias sums
__global__ __launch_bounds__(256) void k_prep(
    const float* __restrict__ bih0, const float* __restrict__ bhh0,
    const float* __restrict__ bih1, const float* __restrict__ bhh1,
    float* __restrict__ bsum0, float* __restrict__ bsum1)
{
    int i = blockIdx.x * 256 + threadIdx.x;
    if (i < G4) {
        bsum0[i] = bih0[i] + bhh0[i];
        bsum1[i] = bih1[i] + bhh1[i];
    }
}

// ---------------------------------------------------------------- weight prep
// convert fp32 -> bf16 bits (same layout)
__global__ __launch_bounds__(256) void k_w_c(
    const float* __restrict__ src, unsigned short* __restrict__ dst, int n)
{
    int i = blockIdx.x * 256 + threadIdx.x;
    if (i < n) dst[i] = f2bf(src[i]);
}
// transpose [K,N] fp32 -> [N,K] bf16
__global__ __launch_bounds__(256) void k_w_t(
    const float* __restrict__ src, unsigned short* __restrict__ dst, int K, int N)
{
    int i = blockIdx.x * 256 + threadIdx.x;
    if (i < K * N) {
        int n = i / K, k = i - n * K;
        dst[i] = f2bf(src[(size_t)k * N + n]);
    }
}

// ---------------------------------------------------------------- Weff = W_in@Wq, beff = b_in@Wq + bq
__global__ __launch_bounds__(256) void k_weff(
    const float* __restrict__ W_in, const float* __restrict__ Wq,
    const float* __restrict__ b_in, const float* __restrict__ bq,
    float* __restrict__ Weff, float* __restrict__ beff)
{
    int idx = blockIdx.x * 256 + threadIdx.x;
    if (idx < M_ * D_) {
        int m = idx / D_, d = idx - m * D_;
        float acc = 0.f;
        for (int j = 0; j < D_; ++j)
            acc += W_in[(size_t)m * D_ + j] * Wq[(size_t)j * D_ + d];
        Weff[idx] = acc;
    }
    if (idx < D_) {
        float acc = bq[idx];
        for (int j = 0; j < D_; ++j)
            acc += b_in[j] * Wq[(size_t)j * D_ + idx];
        beff[idx] = acc;
    }
}

// ---------------------------------------------------------------- MFMA GEMM (bf16 inputs, fp32 acc/out)
// C[M,N] = A' @ B^T + bias, B pre-converted bf16 [N,K].
// mode 0: A' row m = A[m, :] (lda)
// mode 1: A' row m -> (bb=m/TC, t=t0+m%TC): [A[bb*T+t, 0:512] | mel[bb*T+t-1, 0:80] or 0] (K=592 or 512)
// mode 2: A' row bt, k -> (c=k/5, kk=k%5): src[bA*T + tA+kk-2, c] with zero pad (srcC channels)
__global__ __launch_bounds__(256) void k_mfma(
    const float* __restrict__ A, int lda, int t0, const float* __restrict__ mel, int srcC,
    const unsigned short* __restrict__ Bt,
    float* __restrict__ C, int ldc, const float* __restrict__ bias,
    int M, int N, int K, int mode)
{
    __shared__ unsigned short As[128][40];
    __shared__ unsigned short Bs[128][40];
    int tid = threadIdx.x;
    int m0 = blockIdx.x * 128, n0 = blockIdx.y * 128;
    int wave = tid >> 6, lane = tid & 63;
    int wm = (wave >> 1) * 64, wn = (wave & 1) * 64;
    int l15 = lane & 15, quad = lane >> 4;

    f32x4 acc[4][4] = {};

    int srow = tid >> 1;          // staged row 0..127
    int skb  = (tid & 1) * 16;    // k half
    int arow = m0 + srow;
    bool mok = arow < M;
    int arc = mok ? arow : 0;

    const float* Arow = nullptr; const float* Mrow = nullptr;
    int bA = 0, tA = 0;
    if (mode == 0) {
        Arow = A + (size_t)arc * lda;
    } else if (mode == 1) {
        int bb = arc / TC_; int t = t0 + (arc - bb * TC_);
        Arow = A + (size_t)(bb * T_ + t) * D_;
        Mrow = (mel && t > 0) ? mel + (size_t)(bb * T_ + t - 1) * M_ : nullptr;
    } else {
        bA = arc / T_; tA = arc - bA * T_;
    }

    for (int k0 = 0; k0 < K; k0 += 32) {
        // stage A (fp32 -> bf16)
        #pragma unroll
        for (int i = 0; i < 16; ++i) {
            int k = k0 + skb + i;
            float v = 0.f;
            if (mok && k < K) {
                if (mode == 0) v = Arow[k];
                else if (mode == 1) v = (k < D_) ? Arow[k] : (Mrow ? Mrow[k - D_] : 0.f);
                else {
                    int c = k / 5; int kk = k - c * 5;
                    int tt = tA + kk - 2;
                    if (tt >= 0 && tt < T_) v = A[(size_t)(bA * T_ + tt) * srcC + c];
                }
            }
            As[srow][skb + i] = f2bf(v);
        }
        // stage B (already bf16, [N,K])
        {
            int n = n0 + srow;
            bool nok = n < N;
            const unsigned short* bp = Bt + (size_t)(nok ? n : 0) * K;
            #pragma unroll
            for (int i = 0; i < 16; ++i) {
                int k = k0 + skb + i;
                Bs[srow][skb + i] = (nok && k < K) ? bp[k] : (unsigned short)0;
            }
        }
        __syncthreads();

        s16x8 af[4], bfr[4];
        #pragma unroll
        for (int i = 0; i < 4; ++i)
            af[i] = *(const s16x8*)&As[wm + i * 16 + l15][quad * 8];
        #pragma unroll
        for (int j = 0; j < 4; ++j)
            bfr[j] = *(const s16x8*)&Bs[wn + j * 16 + l15][quad * 8];
        #pragma unroll
        for (int i = 0; i < 4; ++i)
            #pragma unroll
            for (int j = 0; j < 4; ++j)
                acc[i][j] = __builtin_amdgcn_mfma_f32_16x16x32_bf16(af[i], bfr[j], acc[i][j], 0, 0, 0);
        __syncthreads();
    }

    #pragma unroll
    for (int i = 0; i < 4; ++i) {
        #pragma unroll
        for (int j = 0; j < 4; ++j) {
            int col = n0 + wn + j * 16 + l15;
            if (col >= N) continue;
            float bv = bias ? bias[col] : 0.f;
            #pragma unroll
            for (int r = 0; r < 4; ++r) {
                int row = m0 + wm + i * 16 + quad * 4 + r;
                if (row >= M) continue;
                C[(size_t)row * ldc + col] = acc[i][j][r] + bv;
            }
        }
    }
}

// ---------------------------------------------------------------- fp32 GEMM (kept for stop head)
__global__ __launch_bounds__(256) void k_gemm(
    const float* __restrict__ A, int lda,
    const float* __restrict__ Bm, int ldb, int transB,
    float* __restrict__ C, int ldc,
    const float* __restrict__ bias,
    int M, int N, int K)
{
    __shared__ float As[16][68];
    __shared__ float Bs[16][68];
    int m0 = blockIdx.x * 64, n0 = blockIdx.y * 64;
    int tid = threadIdx.x;
    int tm = (tid & 15) * 4, tn = (tid >> 4) * 4;
    float acc[4][4] = {};

    for (int k0 = 0; k0 < K; k0 += 16) {
        {
            int f = tid * 4;
            int mm = f >> 4, kk = f & 15;
            bool mok = (m0 + mm) < M;
            const float* ap = A + (size_t)(m0 + mm) * lda + (k0 + kk);
            #pragma unroll
            for (int i = 0; i < 4; ++i) {
                float v = 0.f;
                if (mok && (k0 + kk + i) < K) v = ap[i];
                As[kk + i][mm] = v;
            }
        }
        if (!transB) {
            int f = tid * 4;
            int kk = f >> 6, nn = f & 63;
            bool kok = (k0 + kk) < K;
            const float* bp = Bm + (size_t)(k0 + kk) * ldb + (n0 + nn);
            #pragma unroll
            for (int i = 0; i < 4; ++i) {
                float v = 0.f;
                if (kok && (n0 + nn + i) < N) v = bp[i];
                Bs[kk][nn + i] = v;
            }
        } else {
            int f = tid * 4;
            int nn = f >> 4, kk = f & 15;
            bool nok = (n0 + nn) < N;
            const float* bp = Bm + (size_t)(n0 + nn) * ldb + (k0 + kk);
            #pragma unroll
            for (int i = 0; i < 4; ++i) {
                float v = 0.f;
                if (nok && (k0 + kk + i) < K) v = bp[i];
                Bs[kk + i][nn] = v;
            }
        }
        __syncthreads();
        #pragma unroll
        for (int kk = 0; kk < 16; ++kk) {
            float4 av = *(const float4*)&As[kk][tm];
            float4 bv = *(const float4*)&Bs[kk][tn];
            float a[4] = {av.x, av.y, av.z, av.w};
            float b[4] = {bv.x, bv.y, bv.z, bv.w};
            #pragma unroll
            for (int i = 0; i < 4; ++i)
                #pragma unroll
                for (int j = 0; j < 4; ++j)
                    acc[i][j] += a[i] * b[j];
        }
        __syncthreads();
    }
    #pragma unroll
    for (int i = 0; i < 4; ++i) {
        int m = m0 + tm + i;
        if (m >= M) continue;
        #pragma unroll
        for (int j = 0; j < 4; ++j) {
            int n = n0 + tn + j;
            if (n >= N) continue;
            float v = acc[i][j];
            if (bias) v += bias[n];
            C[(size_t)m * ldc + n] = v;
        }
    }
}

// ---------------------------------------------------------------- attention (fp32, q on the fly)
__global__ __launch_bounds__(256) void k_attn(
    const float* __restrict__ mel,
    const float* __restrict__ Weff, const float* __restrict__ beff,
    const float* __restrict__ Kb, const float* __restrict__ Vb,
    float* __restrict__ ctx)
{
    __shared__ float mrow[4][80];
    __shared__ float qs[4][64];
    __shared__ float ps[4][256];
    int w = threadIdx.x >> 6, lane = threadIdx.x & 63;
    int row = blockIdx.x * 4 + w;
    int t = row % T_; int bh = row / T_;
    int h = bh % H_;  int b = bh / H_;

    {
        float v = 0.f;
        if (t > 0) v = mel[(size_t)(b * T_ + (t - 1)) * M_ + lane];
        mrow[w][lane] = v;
        if (lane < 16) {
            float v2 = 0.f;
            if (t > 0) v2 = mel[(size_t)(b * T_ + (t - 1)) * M_ + 64 + lane];
            mrow[w][64 + lane] = v2;
        }
    }
    __syncthreads();
    {
        int d = h * DH + lane;
        float q = beff[d];
        #pragma unroll 8
        for (int m = 0; m < M_; ++m) q += mrow[w][m] * Weff[(size_t)m * D_ + d];
        qs[w][lane] = q;
    }
    __syncthreads();

    const float* Kbase = Kb + (size_t)(b * S_) * D_ + h * DH;
    float sc[4];
    #pragma unroll
    for (int i = 0; i < 4; ++i) {
        int s = lane + i * 64;
        const float4* kr = (const float4*)(Kbase + (size_t)s * D_);
        float acc = 0.f;
        #pragma unroll
        for (int c4 = 0; c4 < 16; ++c4) {
            float4 kv = kr[c4];
            acc += qs[w][c4 * 4 + 0] * kv.x + qs[w][c4 * 4 + 1] * kv.y
                 + qs[w][c4 * 4 + 2] * kv.z + qs[w][c4 * 4 + 3] * kv.w;
        }
        sc[i] = acc * 0.125f;
    }
    float mx = fmaxf(fmaxf(sc[0], sc[1]), fmaxf(sc[2], sc[3]));
    #pragma unroll
    for (int off = 32; off; off >>= 1) mx = fmaxf(mx, __shfl_xor(mx, off, 64));
    float sum = 0.f;
    #pragma unroll
    for (int i = 0; i < 4; ++i) { sc[i] = __expf(sc[i] - mx); sum += sc[i]; }
    #pragma unroll
    for (int off = 32; off; off >>= 1) sum += __shfl_xor(sum, off, 64);
    float inv = 1.f / sum;
    #pragma unroll
    for (int i = 0; i < 4; ++i) ps[w][lane + i * 64] = sc[i] * inv;
    __syncthreads();

    const float* Vbase = Vb + (size_t)(b * S_) * D_ + h * DH + lane;
    float acc = 0.f;
    for (int s = 0; s < S_; ++s) acc += ps[w][s] * Vbase[(size_t)s * D_];
    ctx[(size_t)(b * T_ + t) * D_ + h * DH + lane] = acc;
}

// ---------------------------------------------------------------- LSTM step (fp32, ping-pong h)
__global__ __launch_bounds__(256) void k_lstm_step(
    const float* __restrict__ xgc,
    const float* __restrict__ Whh,
    float* __restrict__ hseq,
    const float* __restrict__ hprev,
    float* __restrict__ hnext,
    float* __restrict__ cst,
    int t, int tl)
{
    __shared__ float hs[2][512];
    __shared__ float gl[4][2][64];
    int tid = threadIdx.x;
    int dl = tid & 63, g = tid >> 6;
    int b0 = blockIdx.x * 2, d0 = blockIdx.y * 64;
    int d = d0 + dl;

    float acc0 = 0.f, acc1 = 0.f;
    if (t > 0) {
        for (int i = tid; i < 2 * D_; i += 256) {
            int bb = i >> 9, k = i & 511;
            hs[bb][k] = hprev[(size_t)(b0 + bb) * D_ + k];
        }
        __syncthreads();
        const float4* wr = (const float4*)(Whh + (size_t)(g * D_ + d) * D_);
        #pragma unroll 8
        for (int k4 = 0; k4 < 128; ++k4) {
            float4 wv = wr[k4];
            acc0 += wv.x * hs[0][k4 * 4 + 0] + wv.y * hs[0][k4 * 4 + 1]
                  + wv.z * hs[0][k4 * 4 + 2] + wv.w * hs[0][k4 * 4 + 3];
            acc1 += wv.x * hs[1][k4 * 4 + 0] + wv.y * hs[1][k4 * 4 + 1]
                  + wv.z * hs[1][k4 * 4 + 2] + wv.w * hs[1][k4 * 4 + 3];
        }
    }
    gl[g][0][dl] = acc0 + xgc[(size_t)(b0 * TC_ + tl) * G4 + g * D_ + d];
    gl[g][1][dl] = acc1 + xgc[(size_t)((b0 + 1) * TC_ + tl) * G4 + g * D_ + d];
    __syncthreads();
    if (tid < 128) {
        int bb = tid >> 6, dd = tid & 63;
        float iv = gl[0][bb][dd], fv = gl[1][bb][dd];
        float gv = gl[2][bb][dd], ov = gl[3][bb][dd];
        float si = 1.f / (1.f + __expf(-iv));
        float sf = 1.f / (1.f + __expf(-fv));
        float so = 1.f / (1.f + __expf(-ov));
        float tg = tanhf(gv);
        int b = b0 + bb;
        size_t ci = (size_t)b * D_ + d0 + dd;
        float cold = (t == 0) ? 0.f : cst[ci];
        float c = sf * cold + si * tg;
        float h = so * tanhf(c);
        cst[ci] = c;
        hnext[ci] = h;
        hseq[(size_t)(b * T_ + t) * D_ + d0 + dd] = h;
    }
}

// ---------------------------------------------------------------- BN stats
__global__ __launch_bounds__(256) void k_stats(
    const float* __restrict__ x, int C,
    const float* __restrict__ gw, const float* __restrict__ bw,
    float* __restrict__ scale, float* __restrict__ shift)
{
    int c = blockIdx.x;
    float s = 0.f, ss = 0.f;
    for (int r = threadIdx.x; r < BT; r += 256) {
        float v = x[(size_t)r * C + c];
        s += v; ss += v * v;
    }
    __shared__ float rs[256], rq[256];
    rs[threadIdx.x] = s; rq[threadIdx.x] = ss;
    __syncthreads();
    for (int off = 128; off; off >>= 1) {
        if (threadIdx.x < off) {
            rs[threadIdx.x] += rs[threadIdx.x + off];
            rq[threadIdx.x] += rq[threadIdx.x + off];
        }
        __syncthreads();
    }
    if (threadIdx.x == 0) {
        float mean = rs[0] / (float)BT;
        float var  = rq[0] / (float)BT - mean * mean;
        float scv  = gw[c] * rsqrtf(var + 1e-5f);
        scale[c] = scv;
        shift[c] = bw[c] - mean * scv;
    }
}

__global__ __launch_bounds__(256) void k_bnact(
    float* __restrict__ x, int C,
    const float* __restrict__ scale, const float* __restrict__ shift)
{
    int idx = blockIdx.x * 256 + threadIdx.x;
    if (idx < BT * C) {
        int c = idx % C;
        x[idx] = tanhf(scale[c] * x[idx] + shift[c]);
    }
}

__global__ __launch_bounds__(256) void k_residual(
    const float* __restrict__ mel, float* __restrict__ out)
{
    int i = blockIdx.x * 256 + threadIdx.x;
    if (i < BT * M_) out[i] += mel[i];
}

// ================================================================ launch
extern "C" void kernel_launch(void* const* d_in, const int* in_sizes, int n_in,
                              void* d_out, int out_size, void* d_ws, size_t ws_size,
                              hipStream_t stream)
{
    const float* enc    = (const float*)d_in[0];
    const float* mel_t  = (const float*)d_in[1];
    const float* W_in   = (const float*)d_in[2];
    const float* b_in   = (const float*)d_in[3];
    const float* Wq     = (const float*)d_in[4];  const float* bq = (const float*)d_in[5];
    const float* Wk     = (const float*)d_in[6];  const float* bk = (const float*)d_in[7];
    const float* Wv     = (const float*)d_in[8];  const float* bv = (const float*)d_in[9];
    const float* Wo     = (const float*)d_in[10]; const float* bo = (const float*)d_in[11];
    const float* W_ih0  = (const float*)d_in[12]; const float* W_hh0 = (const float*)d_in[13];
    const float* b_ih0  = (const float*)d_in[14]; const float* b_hh0 = (const float*)d_in[15];
    const float* W_ih1  = (const float*)d_in[16]; const float* W_hh1 = (const float*)d_in[17];
    const float* b_ih1  = (const float*)d_in[18]; const float* b_hh1 = (const float*)d_in[19];
    const float* W_mel  = (const float*)d_in[20]; const float* b_mel = (const float*)d_in[21];
    const float* W_stop = (const float*)d_in[22]; const float* b_stop = (const float*)d_in[23];
    const float* pw0 = (const float*)d_in[24]; const float* pb0 = (const float*)d_in[25];
    const float* pw1 = (const float*)d_in[26]; const float* pb1 = (const float*)d_in[27];
    const float* pw2 = (const float*)d_in[28]; const float* pb2 = (const float*)d_in[29];
    const float* pw3 = (const float*)d_in[30]; const float* pb3 = (const float*)d_in[31];
    const float* pw4 = (const float*)d_in[32]; const float* pb4 = (const float*)d_in[33];
    const float* g0 = (const float*)d_in[34]; const float* be0 = (const float*)d_in[35];
    const float* g1 = (const float*)d_in[36]; const float* be1 = (const float*)d_in[37];
    const float* g2 = (const float*)d_in[38]; const float* be2 = (const float*)d_in[39];
    const float* g3 = (const float*)d_in[40]; const float* be3 = (const float*)d_in[41];

    char* p = (char*)d_ws;
    // fp32 region (identical to the verified R4 layout)
    float* Kb  = (float*)(p + 0);
    float* Vb  = (float*)(p + 16777216);
    float* ctx = (float*)(p + 33554432);
    float* ao  = (float*)(p + 0);
    float* xgc = (float*)(p + 26214400);
    float* h1  = (float*)(p + 39321600);
    float* h2  = (float*)(p + 0);
    float* p_a = (float*)(p + 26214400);
    float* p_b = (float*)(p + 0);
    size_t off = 65536000;
    float* bsum0 = (float*)(p + off); off += 8192;
    float* bsum1 = (float*)(p + off); off += 8192;
    float* cbuf  = (float*)(p + off); off += 65536;
    float* hA    = (float*)(p + off); off += 65536;
    float* hB    = (float*)(p + off); off += 65536;
    float* sc0 = (float*)(p + off); off += 2048;
    float* sh0 = (float*)(p + off); off += 2048;
    float* sc1 = (float*)(p + off); off += 2048;
    float* sh1 = (float*)(p + off); off += 2048;
    float* sc2 = (float*)(p + off); off += 2048;
    float* sh2 = (float*)(p + off); off += 2048;
    float* sc3 = (float*)(p + off); off += 2048;
    float* sh3 = (float*)(p + off); off += 2048;
    float* beff = (float*)(p + off); off += 2048;
    float* Weff = (float*)(p + off); off += 163840;
    // bf16 weight tail (~14.9 MB, total ~77 MB)
    unsigned short* Wk_t   = (unsigned short*)(p + off); off += 524288;
    unsigned short* Wv_t   = (unsigned short*)(p + off); off += 524288;
    unsigned short* Wo_t   = (unsigned short*)(p + off); off += 524288;
    unsigned short* Wmel_t = (unsigned short*)(p + off); off += 81920;
    unsigned short* Wih0_b = (unsigned short*)(p + off); off += 2424832;
    unsigned short* Wih1_b = (unsigned short*)(p + off); off += 2097152;
    unsigned short* pw0_b  = (unsigned short*)(p + off); off += 409600;
    unsigned short* pw1_b  = (unsigned short*)(p + off); off += 2621440;
    unsigned short* pw2_b  = (unsigned short*)(p + off); off += 2621440;
    unsigned short* pw3_b  = (unsigned short*)(p + off); off += 2621440;
    unsigned short* pw4_b  = (unsigned short*)(p + off); off += 409600;

    float* out_mel  = (float*)d_out;
    float* out_post = out_mel + (size_t)BT * M_;
    float* out_stop = out_post + (size_t)BT * M_;

    dim3 blk(256);
    auto MF = [&](const float* A, int lda, int t0, const float* mel, int srcC,
                  const unsigned short* Bt, float* C, int ldc, const float* bias,
                  int M, int N, int K, int mode) {
        dim3 g((M + 127) / 128, (N + 127) / 128);
        k_mfma<<<g, blk, 0, stream>>>(A, lda, t0, mel, srcC, Bt, C, ldc, bias, M, N, K, mode);
    };

    // ---- weight prep
    k_prep<<<8, blk, 0, stream>>>(b_ih0, b_hh0, b_ih1, b_hh1, bsum0, bsum1);
    k_weff<<<160, blk, 0, stream>>>(W_in, Wq, b_in, bq, Weff, beff);
    k_w_t<<<1024, blk, 0, stream>>>(Wk, Wk_t, D_, D_);
    k_w_t<<<1024, blk, 0, stream>>>(Wv, Wv_t, D_, D_);
    k_w_t<<<1024, blk, 0, stream>>>(Wo, Wo_t, D_, D_);
    k_w_t<<<160, blk, 0, stream>>>(W_mel, Wmel_t, D_, M_);
    k_w_c<<<4736, blk, 0, stream>>>(W_ih0, Wih0_b, G4 * DM);
    k_w_c<<<4096, blk, 0, stream>>>(W_ih1, Wih1_b, G4 * D_);
    k_w_c<<<800, blk, 0, stream>>>(pw0, pw0_b, 512 * 400);
    k_w_c<<<5120, blk, 0, stream>>>(pw1, pw1_b, 512 * 2560);
    k_w_c<<<5120, blk, 0, stream>>>(pw2, pw2_b, 512 * 2560);
    k_w_c<<<5120, blk, 0, stream>>>(pw3, pw3_b, 512 * 2560);
    k_w_c<<<800, blk, 0, stream>>>(pw4, pw4_b, 80 * 2560);

    // ---- K/V projections (MFMA)
    MF(enc, D_, 0, nullptr, 0, Wk_t, Kb, D_, bk, BS, D_, D_, 0);
    MF(enc, D_, 0, nullptr, 0, Wv_t, Vb, D_, bv, BS, D_, D_, 0);

    // ---- attention (fp32)
    k_attn<<<(B_ * H_ * T_) / 4, blk, 0, stream>>>(mel_t, Weff, beff, Kb, Vb, ctx);

    // ---- attn_out = ctx @ Wo + bo
    MF(ctx, D_, 0, nullptr, 0, Wo_t, ao, D_, bo, BT, D_, D_, 0);

    dim3 lg(16, 8);
    float* hb[2] = {hA, hB};

    // ---- LSTM layer 0 (chunked xg via MFMA mode 1, K=592 with virtual mel concat)
    for (int c = 0; c < T_ / TC_; ++c) {
        MF(ao, 0, c * TC_, mel_t, 0, Wih0_b, xgc, G4, bsum0, B_ * TC_, G4, DM, 1);
        for (int tl = 0; tl < TC_; ++tl) {
            int t = c * TC_ + tl;
            k_lstm_step<<<lg, blk, 0, stream>>>(xgc, W_hh0, h1, hb[t & 1], hb[(t + 1) & 1], cbuf, t, tl);
        }
    }
    // ---- LSTM layer 1 (K=512)
    for (int c = 0; c < T_ / TC_; ++c) {
        MF(h1, 0, c * TC_, nullptr, 0, Wih1_b, xgc, G4, bsum1, B_ * TC_, G4, D_, 1);
        for (int tl = 0; tl < TC_; ++tl) {
            int t = c * TC_ + tl;
            k_lstm_step<<<lg, blk, 0, stream>>>(xgc, W_hh1, h2, hb[t & 1], hb[(t + 1) & 1], cbuf, t, tl);
        }
    }

    // ---- heads
    MF(h2, D_, 0, nullptr, 0, Wmel_t, out_mel, M_, b_mel, BT, M_, D_, 0);
    {
        dim3 g((BT + 63) / 64, 1);
        k_gemm<<<g, blk, 0, stream>>>(h2, D_, W_stop, 1, 0, out_stop, 1, b_stop, BT, 1, D_);
    }

    // ---- postnet (conv via MFMA mode 2)
    int gD = (BT * D_ + 255) / 256;

    MF(out_mel, 0, 0, nullptr, M_, pw0_b, p_a, D_, pb0, BT, D_, M_ * 5, 2);
    k_stats<<<512, blk, 0, stream>>>(p_a, D_, g0, be0, sc0, sh0);
    k_bnact<<<gD, blk, 0, stream>>>(p_a, D_, sc0, sh0);

    MF(p_a, 0, 0, nullptr, D_, pw1_b, p_b, D_, pb1, BT, D_, D_ * 5, 2);
    k_stats<<<512, blk, 0, stream>>>(p_b, D_, g1, be1, sc1, sh1);
    k_bnact<<<gD, blk, 0, stream>>>(p_b, D_, sc1, sh1);

    MF(p_b, 0, 0, nullptr, D_, pw2_b, p_a, D_, pb2, BT, D_, D_ * 5, 2);
    k_stats<<<512, blk, 0, stream>>>(p_a, D_, g2, be2, sc2, sh2);
    k_bnact<<<gD, blk, 0, stream>>>(p_a, D_, sc2, sh2);

    MF(p_a, 0, 0, nullptr, D_, pw3_b, p_b, D_, pb3, BT, D_, D_ * 5, 2);
    k_stats<<<512, blk, 0, stream>>>(p_b, D_, g3, be3, sc3, sh3);
    k_bnact<<<gD, blk, 0, stream>>>(p_b, D_, sc3, sh3);

    MF(p_b, 0, 0, nullptr, D_, pw4_b, out_post, M_, pb4, BT, M_, D_ * 5, 2);
    k_residual<<<4000, blk, 0, stream>>>(out_mel, out_post);
}

// Round 6
// 11118.413 us; speedup vs baseline: 2.1039x; 2.0146x over previous
//
#include <hip/hip_runtime.h>
#include <math.h>

#define B_  32
#define S_  256
#define T_  400
#define M_  80
#define D_  512
#define H_  8
#define DH  64
#define BT  (B_*T_)    // 12800
#define BS  (B_*S_)    // 8192
#define G4  (4*D_)     // 2048
#define DM  (D_+M_)    // 592
#define NB_ 64         // blocks in persistent LSTM kernel

typedef short s16x8 __attribute__((ext_vector_type(8)));
typedef float f32x4 __attribute__((ext_vector_type(4)));

__device__ __forceinline__ unsigned short f2bf(float f) {
    union { float f; unsigned u; } v; v.f = f;
    unsigned r = v.u + 0x7fffu + ((v.u >> 16) & 1u);
    return (unsigned short)(r >> 16);
}
__device__ __forceinline__ float us2f(unsigned short u) {
    union { unsigned i; float f; } v; v.i = ((unsigned)u) << 16; return v.f;
}
__device__ __forceinline__ uint4 pack8(const float* f) {
    uint4 u;
    u.x = (unsigned)f2bf(f[0]) | ((unsigned)f2bf(f[1]) << 16);
    u.y = (unsigned)f2bf(f[2]) | ((unsigned)f2bf(f[3]) << 16);
    u.z = (unsigned)f2bf(f[4]) | ((unsigned)f2bf(f[5]) << 16);
    u.w = (unsigned)f2bf(f[6]) | ((unsigned)f2bf(f[7]) << 16);
    return u;
}

// ---------------------------------------------------------------- prep: bias sums + barrier zero
__global__ __launch_bounds__(256) void k_prep(
    const float* __restrict__ bih0, const float* __restrict__ bhh0,
    const float* __restrict__ bih1, const float* __restrict__ bhh1,
    float* __restrict__ bsum0, float* __restrict__ bsum1,
    int* __restrict__ bar0, int* __restrict__ bar1)
{
    int i = blockIdx.x * 256 + threadIdx.x;
    if (i < G4) {
        bsum0[i] = bih0[i] + bhh0[i];
        bsum1[i] = bih1[i] + bhh1[i];
    }
    if (i == 0) { *bar0 = 0; *bar1 = 0; }
}

// ---------------------------------------------------------------- weight prep
__global__ __launch_bounds__(256) void k_w_c(
    const float* __restrict__ src, unsigned short* __restrict__ dst, int n)
{
    int i = blockIdx.x * 256 + threadIdx.x;
    if (i < n) dst[i] = f2bf(src[i]);
}
// transpose [K,N] fp32 -> [N,K] bf16
__global__ __launch_bounds__(256) void k_w_t(
    const float* __restrict__ src, unsigned short* __restrict__ dst, int K, int N)
{
    int i = blockIdx.x * 256 + threadIdx.x;
    if (i < K * N) {
        int n = i / K, k = i - n * K;
        dst[i] = f2bf(src[(size_t)k * N + n]);
    }
}

// ---------------------------------------------------------------- Weff = W_in@Wq, beff = b_in@Wq + bq
__global__ __launch_bounds__(256) void k_weff(
    const float* __restrict__ W_in, const float* __restrict__ Wq,
    const float* __restrict__ b_in, const float* __restrict__ bq,
    float* __restrict__ Weff, float* __restrict__ beff)
{
    int idx = blockIdx.x * 256 + threadIdx.x;
    if (idx < M_ * D_) {
        int m = idx / D_, d = idx - m * D_;
        float acc = 0.f;
        for (int j = 0; j < D_; ++j)
            acc += W_in[(size_t)m * D_ + j] * Wq[(size_t)j * D_ + d];
        Weff[idx] = acc;
    }
    if (idx < D_) {
        float acc = bq[idx];
        for (int j = 0; j < D_; ++j)
            acc += b_in[j] * Wq[(size_t)j * D_ + idx];
        beff[idx] = acc;
    }
}

// ---------------------------------------------------------------- MFMA GEMM
// C[M,N] = A' @ B^T + bias; B bf16 [N,K]. fp32 acc; out fp32 or bf16 (cbf16).
// mode 0: A' row m = A[m,:] (lda), fp32 or bf16 (abf16)
// mode 1: A' row m=bt: [A[bt,0:512] fp32 | mel[bt-1,0:80] or 0]  (K=592)
// mode 2: conv im2col gather: k -> (c=k/5, kk=k%5): A[bA*T+tA+kk-2, c], fp32, srcC channels
__global__ __launch_bounds__(256) void k_mfma(
    const void* __restrict__ Aptr, int lda, const float* __restrict__ mel, int srcC,
    const unsigned short* __restrict__ Bt,
    void* __restrict__ Cptr, int ldc, const float* __restrict__ bias,
    int M, int N, int K, int mode, int abf16, int cbf16)
{
    __shared__ unsigned short As[128][40];
    __shared__ unsigned short Bs[128][40];
    int tid = threadIdx.x;
    int m0 = blockIdx.x * 128, n0 = blockIdx.y * 128;
    int wave = tid >> 6, lane = tid & 63;
    int wm = (wave >> 1) * 64, wn = (wave & 1) * 64;
    int l15 = lane & 15, quad = lane >> 4;

    f32x4 acc[4][4] = {};

    int srow = tid >> 1, half = tid & 1;
    int arow = m0 + srow;
    bool mok = arow < M;
    int arc = mok ? arow : 0;

    const float* Af = (const float*)Aptr;
    const unsigned short* Ab = (const unsigned short*)Aptr;
    const float* Arow_f = nullptr; const unsigned short* Arow_b = nullptr;
    const float* Mrow = nullptr;
    int bA = 0, tA = 0;
    if (mode == 2) { bA = arc / T_; tA = arc - bA * T_; }
    else {
        if (abf16) Arow_b = Ab + (size_t)arc * lda;
        else       Arow_f = Af + (size_t)arc * lda;
        if (mode == 1) {
            int tt = arc % T_;
            if (tt > 0) Mrow = mel + (size_t)(arc - 1) * M_;
        }
    }
    int brow = n0 + srow;
    bool nok = brow < N;
    const unsigned short* Brow = Bt + (size_t)(nok ? brow : 0) * K;
    const uint4 z4 = make_uint4(0, 0, 0, 0);

    for (int k0 = 0; k0 < K; k0 += 32) {
        int ks = k0 + half * 16;
        uint4 a0, a1;
        if (!mok || ks >= K) { a0 = z4; a1 = z4; }
        else if (mode == 2) {
            float tf[16];
            #pragma unroll
            for (int i = 0; i < 16; ++i) {
                int ka = ks + i;
                int c = ka / 5, kk = ka - c * 5;
                int tt = tA + kk - 2;
                tf[i] = (tt >= 0 && tt < T_) ? Af[(size_t)(bA * T_ + tt) * srcC + c] : 0.f;
            }
            a0 = pack8(tf); a1 = pack8(tf + 8);
        } else if (abf16) {
            const uint4* s = (const uint4*)(Arow_b + ks);
            a0 = s[0]; a1 = s[1];
        } else if (mode == 1 && ks >= D_) {
            if (Mrow) {
                float tf[16];
                const float4* s = (const float4*)(Mrow + (ks - D_));
                #pragma unroll
                for (int i = 0; i < 4; ++i) {
                    float4 v = s[i];
                    tf[i*4+0] = v.x; tf[i*4+1] = v.y; tf[i*4+2] = v.z; tf[i*4+3] = v.w;
                }
                a0 = pack8(tf); a1 = pack8(tf + 8);
            } else { a0 = z4; a1 = z4; }
        } else {
            float tf[16];
            const float4* s = (const float4*)(Arow_f + ks);
            #pragma unroll
            for (int i = 0; i < 4; ++i) {
                float4 v = s[i];
                tf[i*4+0] = v.x; tf[i*4+1] = v.y; tf[i*4+2] = v.z; tf[i*4+3] = v.w;
            }
            a0 = pack8(tf); a1 = pack8(tf + 8);
        }
        *(uint4*)&As[srow][half * 16]     = a0;
        *(uint4*)&As[srow][half * 16 + 8] = a1;

        uint4 b0, b1;
        if (!nok || ks >= K) { b0 = z4; b1 = z4; }
        else {
            const uint4* s = (const uint4*)(Brow + ks);
            b0 = s[0]; b1 = s[1];
        }
        *(uint4*)&Bs[srow][half * 16]     = b0;
        *(uint4*)&Bs[srow][half * 16 + 8] = b1;
        __syncthreads();

        s16x8 af[4], bfr[4];
        #pragma unroll
        for (int i = 0; i < 4; ++i)
            af[i] = *(const s16x8*)&As[wm + i * 16 + l15][quad * 8];
        #pragma unroll
        for (int j = 0; j < 4; ++j)
            bfr[j] = *(const s16x8*)&Bs[wn + j * 16 + l15][quad * 8];
        #pragma unroll
        for (int i = 0; i < 4; ++i)
            #pragma unroll
            for (int j = 0; j < 4; ++j)
                acc[i][j] = __builtin_amdgcn_mfma_f32_16x16x32_bf16(af[i], bfr[j], acc[i][j], 0, 0, 0);
        __syncthreads();
    }

    #pragma unroll
    for (int i = 0; i < 4; ++i) {
        #pragma unroll
        for (int j = 0; j < 4; ++j) {
            int col = n0 + wn + j * 16 + l15;
            if (col >= N) continue;
            float bv = bias ? bias[col] : 0.f;
            #pragma unroll
            for (int r = 0; r < 4; ++r) {
                int row = m0 + wm + i * 16 + quad * 4 + r;
                if (row >= M) continue;
                float v = acc[i][j][r] + bv;
                if (cbf16) ((unsigned short*)Cptr)[(size_t)row * ldc + col] = f2bf(v);
                else       ((float*)Cptr)[(size_t)row * ldc + col] = v;
            }
        }
    }
}

// ---------------------------------------------------------------- attention (fp32, q on the fly)
__global__ __launch_bounds__(256) void k_attn(
    const float* __restrict__ mel,
    const float* __restrict__ Weff, const float* __restrict__ beff,
    const float* __restrict__ Kb, const float* __restrict__ Vb,
    float* __restrict__ ctx)
{
    __shared__ float mrow[4][80];
    __shared__ float qs[4][64];
    __shared__ float ps[4][256];
    int w = threadIdx.x >> 6, lane = threadIdx.x & 63;
    int row = blockIdx.x * 4 + w;
    int t = row % T_; int bh = row / T_;
    int h = bh % H_;  int b = bh / H_;

    {
        float v = 0.f;
        if (t > 0) v = mel[(size_t)(b * T_ + (t - 1)) * M_ + lane];
        mrow[w][lane] = v;
        if (lane < 16) {
            float v2 = 0.f;
            if (t > 0) v2 = mel[(size_t)(b * T_ + (t - 1)) * M_ + 64 + lane];
            mrow[w][64 + lane] = v2;
        }
    }
    __syncthreads();
    {
        int d = h * DH + lane;
        float q = beff[d];
        #pragma unroll 8
        for (int m = 0; m < M_; ++m) q += mrow[w][m] * Weff[(size_t)m * D_ + d];
        qs[w][lane] = q;
    }
    __syncthreads();

    const float* Kbase = Kb + (size_t)(b * S_) * D_ + h * DH;
    float sc[4];
    #pragma unroll
    for (int i = 0; i < 4; ++i) {
        int s = lane + i * 64;
        const float4* kr = (const float4*)(Kbase + (size_t)s * D_);
        float acc = 0.f;
        #pragma unroll
        for (int c4 = 0; c4 < 16; ++c4) {
            float4 kv = kr[c4];
            acc += qs[w][c4 * 4 + 0] * kv.x + qs[w][c4 * 4 + 1] * kv.y
                 + qs[w][c4 * 4 + 2] * kv.z + qs[w][c4 * 4 + 3] * kv.w;
        }
        sc[i] = acc * 0.125f;
    }
    float mx = fmaxf(fmaxf(sc[0], sc[1]), fmaxf(sc[2], sc[3]));
    #pragma unroll
    for (int off = 32; off; off >>= 1) mx = fmaxf(mx, __shfl_xor(mx, off, 64));
    float sum = 0.f;
    #pragma unroll
    for (int i = 0; i < 4; ++i) { sc[i] = __expf(sc[i] - mx); sum += sc[i]; }
    #pragma unroll
    for (int off = 32; off; off >>= 1) sum += __shfl_xor(sum, off, 64);
    float inv = 1.f / sum;
    #pragma unroll
    for (int i = 0; i < 4; ++i) ps[w][lane + i * 64] = sc[i] * inv;
    __syncthreads();

    const float* Vbase = Vb + (size_t)(b * S_) * D_ + h * DH + lane;
    float acc = 0.f;
    for (int s = 0; s < S_; ++s) acc += ps[w][s] * Vbase[(size_t)s * D_];
    ctx[(size_t)(b * T_ + t) * D_ + h * DH + lane] = acc;
}

// ---------------------------------------------------------------- persistent LSTM layer
// 64 blocks, block bd owns dims d0=bd*8 (8 dims x 4 gates = 32 Whh rows, LDS-pinned bf16).
// Per step: MFMA matvec gates[32x32] = Ws . h_prev, nonlinearity (c in regs), h via
// global ping-pong (bf16), manual device-scope grid barrier (monotone atomic counter).
__global__ __launch_bounds__(256) void k_lstm_coop(
    const unsigned short* __restrict__ xg,    // [B,T,2048] bf16 (biases folded)
    const unsigned short* __restrict__ Whh,   // [2048,512] bf16
    unsigned short* __restrict__ hseq,        // [B,T,512] bf16 out
    unsigned short* __restrict__ hpp,         // [2][32*512] bf16 ping-pong
    int* __restrict__ bar)
{
    __shared__ unsigned short Ws[32][520];    // rows: g*8+dl, padded (+8) for bank spread
    __shared__ float gl[32][32];
    int tid = threadIdx.x;
    int bd = blockIdx.x;
    int d0 = bd * 8;

    { // load Whh slice into LDS (32 rows x 512 bf16)
        int r = tid >> 3, seg = tid & 7;
        int g = r >> 3, dl = r & 7;
        const uint4* src = (const uint4*)(Whh + ((size_t)(g * 512 + d0 + dl) * 512 + seg * 64));
        uint4* dst = (uint4*)&Ws[r][seg * 64];
        #pragma unroll
        for (int j = 0; j < 8; ++j) dst[j] = src[j];
    }
    int lane = tid & 63;
    int l15 = lane & 15, quad = lane >> 4;
    int mt = (tid >> 6) >> 1, nt = (tid >> 6) & 1;
    int dl_u = tid >> 5, b_u = tid & 31;      // update: 8 dims x 32 batches
    float creg = 0.f;
    __syncthreads();

    for (int t = 0; t < T_; ++t) {
        // prefetch xg gates for this thread's (dim,batch)
        float xv[4];
        {
            const unsigned short* xr = xg + ((size_t)(b_u * T_ + t) * G4) + d0 + dl_u;
            #pragma unroll
            for (int g = 0; g < 4; ++g) xv[g] = us2f(xr[g * 512]);
        }
        if (t > 0) {
            const unsigned short* hrd = hpp + ((t + 1) & 1) * (32 * 512);
            f32x4 acc = {};
            #pragma unroll 4
            for (int k0 = 0; k0 < 512; k0 += 32) {
                s16x8 af = *(const s16x8*)&Ws[mt * 16 + l15][k0 + quad * 8];
                s16x8 bf = *(const s16x8*)(hrd + (size_t)(nt * 16 + l15) * 512 + k0 + quad * 8);
                acc = __builtin_amdgcn_mfma_f32_16x16x32_bf16(af, bf, acc, 0, 0, 0);
            }
            #pragma unroll
            for (int r = 0; r < 4; ++r)
                gl[mt * 16 + quad * 4 + r][nt * 16 + l15] = acc[r];
        }
        __syncthreads();
        {
            float iv = xv[0], fv = xv[1], gv = xv[2], ov = xv[3];
            if (t > 0) {
                iv += gl[0 * 8 + dl_u][b_u];
                fv += gl[1 * 8 + dl_u][b_u];
                gv += gl[2 * 8 + dl_u][b_u];
                ov += gl[3 * 8 + dl_u][b_u];
            }
            float si = 1.f / (1.f + __expf(-iv));
            float sf = 1.f / (1.f + __expf(-fv));
            float so = 1.f / (1.f + __expf(-ov));
            float tg = tanhf(gv);
            float c = sf * ((t > 0) ? creg : 0.f) + si * tg;
            float h = so * tanhf(c);
            creg = c;
            unsigned short hb = f2bf(h);
            hpp[(t & 1) * (32 * 512) + (size_t)b_u * 512 + d0 + dl_u] = hb;
            hseq[((size_t)b_u * T_ + t) * 512 + d0 + dl_u] = hb;
        }
        __syncthreads();                       // gl reads done; h stores drained (vmcnt)
        if (tid == 0) {
            __threadfence();                   // release: writeback L2 (cross-XCD visibility)
            __hip_atomic_fetch_add(bar, 1, __ATOMIC_RELEASE, __HIP_MEMORY_SCOPE_AGENT);
            int target = NB_ * (t + 1);
            while (__hip_atomic_load(bar, __ATOMIC_RELAXED, __HIP_MEMORY_SCOPE_AGENT) < target) {}
            __threadfence();                   // acquire: invalidate stale L1/L2
        }
        __syncthreads();
    }
}

// ---------------------------------------------------------------- stop head (h2 bf16 . W_stop)
__global__ __launch_bounds__(256) void k_stop(
    const unsigned short* __restrict__ h2, const float* __restrict__ W,
    const float* __restrict__ bsc, float* __restrict__ out)
{
    int w = threadIdx.x >> 6, lane = threadIdx.x & 63;
    int row = blockIdx.x * 4 + w;
    const unsigned short* hr = h2 + (size_t)row * 512 + lane * 8;
    float acc = 0.f;
    #pragma unroll
    for (int j = 0; j < 8; ++j) acc += us2f(hr[j]) * W[lane * 8 + j];
    #pragma unroll
    for (int off = 32; off; off >>= 1) acc += __shfl_xor(acc, off, 64);
    if (lane == 0) out[row] = acc + bsc[0];
}

// ---------------------------------------------------------------- BN stats (training mode)
__global__ __launch_bounds__(256) void k_stats(
    const float* __restrict__ x, int C,
    const float* __restrict__ gw, const float* __restrict__ bw,
    float* __restrict__ scale, float* __restrict__ shift)
{
    int c = blockIdx.x;
    float s = 0.f, ss = 0.f;
    for (int r = threadIdx.x; r < BT; r += 256) {
        float v = x[(size_t)r * C + c];
        s += v; ss += v * v;
    }
    __shared__ float rs[256], rq[256];
    rs[threadIdx.x] = s; rq[threadIdx.x] = ss;
    __syncthreads();
    for (int off = 128; off; off >>= 1) {
        if (threadIdx.x < off) {
            rs[threadIdx.x] += rs[threadIdx.x + off];
            rq[threadIdx.x] += rq[threadIdx.x + off];
        }
        __syncthreads();
    }
    if (threadIdx.x == 0) {
        float mean = rs[0] / (float)BT;
        float var  = rq[0] / (float)BT - mean * mean;
        float scv  = gw[c] * rsqrtf(var + 1e-5f);
        scale[c] = scv;
        shift[c] = bw[c] - mean * scv;
    }
}

__global__ __launch_bounds__(256) void k_bnact(
    float* __restrict__ x, int C,
    const float* __restrict__ scale, const float* __restrict__ shift)
{
    int idx = blockIdx.x * 256 + threadIdx.x;
    if (idx < BT * C) {
        int c = idx % C;
        x[idx] = tanhf(scale[c] * x[idx] + shift[c]);
    }
}

__global__ __launch_bounds__(256) void k_residual(
    const float* __restrict__ mel, float* __restrict__ out)
{
    int i = blockIdx.x * 256 + threadIdx.x;
    if (i < BT * M_) out[i] += mel[i];
}

// ================================================================ launch
extern "C" void kernel_launch(void* const* d_in, const int* in_sizes, int n_in,
                              void* d_out, int out_size, void* d_ws, size_t ws_size,
                              hipStream_t stream)
{
    const float* enc    = (const float*)d_in[0];
    const float* mel_t  = (const float*)d_in[1];
    const float* W_in   = (const float*)d_in[2];
    const float* b_in   = (const float*)d_in[3];
    const float* Wq     = (const float*)d_in[4];  const float* bq = (const float*)d_in[5];
    const float* Wk     = (const float*)d_in[6];  const float* bk = (const float*)d_in[7];
    const float* Wv     = (const float*)d_in[8];  const float* bv = (const float*)d_in[9];
    const float* Wo     = (const float*)d_in[10]; const float* bo = (const float*)d_in[11];
    const float* W_ih0  = (const float*)d_in[12]; const float* W_hh0 = (const float*)d_in[13];
    const float* b_ih0  = (const float*)d_in[14]; const float* b_hh0 = (const float*)d_in[15];
    const float* W_ih1  = (const float*)d_in[16]; const float* W_hh1 = (const float*)d_in[17];
    const float* b_ih1  = (const float*)d_in[18]; const float* b_hh1 = (const float*)d_in[19];
    const float* W_mel  = (const float*)d_in[20]; const float* b_mel = (const float*)d_in[21];
    const float* W_stop = (const float*)d_in[22]; const float* b_stop = (const float*)d_in[23];
    const float* pw0 = (const float*)d_in[24]; const float* pb0 = (const float*)d_in[25];
    const float* pw1 = (const float*)d_in[26]; const float* pb1 = (const float*)d_in[27];
    const float* pw2 = (const float*)d_in[28]; const float* pb2 = (const float*)d_in[29];
    const float* pw3 = (const float*)d_in[30]; const float* pb3 = (const float*)d_in[31];
    const float* pw4 = (const float*)d_in[32]; const float* pb4 = (const float*)d_in[33];
    const float* g0 = (const float*)d_in[34]; const float* be0 = (const float*)d_in[35];
    const float* g1 = (const float*)d_in[36]; const float* be1 = (const float*)d_in[37];
    const float* g2 = (const float*)d_in[38]; const float* be2 = (const float*)d_in[39];
    const float* g3 = (const float*)d_in[40]; const float* be3 = (const float*)d_in[41];

    char* p = (char*)d_ws;
    // ---- main region, peak 78.6 MB; lifetimes verified against launch order:
    //  Kb[0,16.8M)+Vb[16.8,33.6M) dead after attn; ctx[33.6,59.8M) dead after ao GEMM
    //  ao[0,26.2M) dead after xg0 GEMM; xg0[26.2,78.6M) bf16, dead after L0
    //  h1seq[0,13.1M) bf16 dead after xg1 GEMM; xg1[13.1,65.5M) bf16 dead after L1
    //  h2seq[65.5,78.6M) bf16; postnet p_a[0,26.2M), p_b[26.2,52.4M) fp32
    float* Kb  = (float*)(p + 0);
    float* Vb  = (float*)(p + 16777216);
    float* ctx = (float*)(p + 33554432);
    float* ao  = (float*)(p + 0);
    unsigned short* xg0   = (unsigned short*)(p + 26214400);
    unsigned short* h1seq = (unsigned short*)(p + 0);
    unsigned short* xg1   = (unsigned short*)(p + 13107200);
    unsigned short* h2seq = (unsigned short*)(p + 65536000);
    float* p_a = (float*)(p + 0);
    float* p_b = (float*)(p + 26214400);
    size_t off = 78643200;
    float* bsum0 = (float*)(p + off); off += 8192;
    float* bsum1 = (float*)(p + off); off += 8192;
    unsigned short* hpp = (unsigned short*)(p + off); off += 65536;
    float* beff = (float*)(p + off); off += 2048;
    float* Weff = (float*)(p + off); off += 163840;
    float* sc0 = (float*)(p + off); off += 2048;
    float* sh0 = (float*)(p + off); off += 2048;
    float* sc1 = (float*)(p + off); off += 2048;
    float* sh1 = (float*)(p + off); off += 2048;
    float* sc2 = (float*)(p + off); off += 2048;
    float* sh2 = (float*)(p + off); off += 2048;
    float* sc3 = (float*)(p + off); off += 2048;
    float* sh3 = (float*)(p + off); off += 2048;
    int* bar0 = (int*)(p + off); off += 128;
    int* bar1 = (int*)(p + off); off += 128;
    unsigned short* Wk_t   = (unsigned short*)(p + off); off += 524288;
    unsigned short* Wv_t   = (unsigned short*)(p + off); off += 524288;
    unsigned short* Wo_t   = (unsigned short*)(p + off); off += 524288;
    unsigned short* Wmel_t = (unsigned short*)(p + off); off += 81920;
    unsigned short* Wih0_b = (unsigned short*)(p + off); off += 2424832;
    unsigned short* Wih1_b = (unsigned short*)(p + off); off += 2097152;
    unsigned short* Whh0_b = (unsigned short*)(p + off); off += 2097152;
    unsigned short* Whh1_b = (unsigned short*)(p + off); off += 2097152;
    unsigned short* pw0_b  = (unsigned short*)(p + off); off += 409600;
    unsigned short* pw1_b  = (unsigned short*)(p + off); off += 2621440;
    unsigned short* pw2_b  = (unsigned short*)(p + off); off += 2621440;
    unsigned short* pw3_b  = (unsigned short*)(p + off); off += 2621440;
    unsigned short* pw4_b  = (unsigned short*)(p + off); off += 409600;
    // total ~98 MB

    float* out_mel  = (float*)d_out;
    float* out_post = out_mel + (size_t)BT * M_;
    float* out_stop = out_post + (size_t)BT * M_;

    dim3 blk(256);
    auto MF = [&](const void* A, int lda, const float* mel, int srcC,
                  const unsigned short* Bt, void* C, int ldc, const float* bias,
                  int M, int N, int K, int mode, int abf16, int cbf16) {
        dim3 g((M + 127) / 128, (N + 127) / 128);
        k_mfma<<<g, blk, 0, stream>>>(A, lda, mel, srcC, Bt, C, ldc, bias, M, N, K, mode, abf16, cbf16);
    };

    // ---- prep
    k_prep<<<8, blk, 0, stream>>>(b_ih0, b_hh0, b_ih1, b_hh1, bsum0, bsum1, bar0, bar1);
    k_weff<<<160, blk, 0, stream>>>(W_in, Wq, b_in, bq, Weff, beff);
    k_w_t<<<1024, blk, 0, stream>>>(Wk, Wk_t, D_, D_);
    k_w_t<<<1024, blk, 0, stream>>>(Wv, Wv_t, D_, D_);
    k_w_t<<<1024, blk, 0, stream>>>(Wo, Wo_t, D_, D_);
    k_w_t<<<160, blk, 0, stream>>>(W_mel, Wmel_t, D_, M_);
    k_w_c<<<4736, blk, 0, stream>>>(W_ih0, Wih0_b, G4 * DM);
    k_w_c<<<4096, blk, 0, stream>>>(W_ih1, Wih1_b, G4 * D_);
    k_w_c<<<4096, blk, 0, stream>>>(W_hh0, Whh0_b, G4 * D_);
    k_w_c<<<4096, blk, 0, stream>>>(W_hh1, Whh1_b, G4 * D_);
    k_w_c<<<800, blk, 0, stream>>>(pw0, pw0_b, 512 * 400);
    k_w_c<<<5120, blk, 0, stream>>>(pw1, pw1_b, 512 * 2560);
    k_w_c<<<5120, blk, 0, stream>>>(pw2, pw2_b, 512 * 2560);
    k_w_c<<<5120, blk, 0, stream>>>(pw3, pw3_b, 512 * 2560);
    k_w_c<<<800, blk, 0, stream>>>(pw4, pw4_b, 80 * 2560);

    // ---- K/V projections
    MF(enc, D_, nullptr, 0, Wk_t, Kb, D_, bk, BS, D_, D_, 0, 0, 0);
    MF(enc, D_, nullptr, 0, Wv_t, Vb, D_, bv, BS, D_, D_, 0, 0, 0);

    // ---- attention
    k_attn<<<(B_ * H_ * T_) / 4, blk, 0, stream>>>(mel_t, Weff, beff, Kb, Vb, ctx);

    // ---- attn_out = ctx @ Wo + bo
    MF(ctx, D_, nullptr, 0, Wo_t, ao, D_, bo, BT, D_, D_, 0, 0, 0);

    // ---- xg0 (full T, bf16 out, virtual [ao | dec_in] concat, K=592)
    MF(ao, D_, mel_t, 0, Wih0_b, xg0, G4, bsum0, BT, G4, DM, 1, 0, 1);

    // ---- LSTM layer 0 (single persistent launch)
    k_lstm_coop<<<NB_, blk, 0, stream>>>(xg0, Whh0_b, h1seq, hpp, bar0);

    // ---- xg1 = h1seq(bf16) @ W_ih1^T + bsum1
    MF(h1seq, D_, nullptr, 0, Wih1_b, xg1, G4, bsum1, BT, G4, D_, 0, 1, 1);

    // ---- LSTM layer 1
    k_lstm_coop<<<NB_, blk, 0, stream>>>(xg1, Whh1_b, h2seq, hpp, bar1);

    // ---- heads
    MF(h2seq, D_, nullptr, 0, Wmel_t, out_mel, M_, b_mel, BT, M_, D_, 0, 1, 0);
    k_stop<<<BT / 4, blk, 0, stream>>>(h2seq, W_stop, b_stop, out_stop);

    // ---- postnet
    int gD = (BT * D_ + 255) / 256;

    MF(out_mel, 0, nullptr, M_, pw0_b, p_a, D_, pb0, BT, D_, M_ * 5, 2, 0, 0);
    k_stats<<<512, blk, 0, stream>>>(p_a, D_, g0, be0, sc0, sh0);
    k_bnact<<<gD, blk, 0, stream>>>(p_a, D_, sc0, sh0);

    MF(p_a, 0, nullptr, D_, pw1_b, p_b, D_, pb1, BT, D_, D_ * 5, 2, 0, 0);
    k_stats<<<512, blk, 0, stream>>>(p_b, D_, g1, be1, sc1, sh1);
    k_bnact<<<gD, blk, 0, stream>>>(p_b, D_, sc1, sh1);

    MF(p_b, 0, nullptr, D_, pw2_b, p_a, D_, pb2, BT, D_, D_ * 5, 2, 0, 0);
    k_stats<<<512, blk, 0, stream>>>(p_a, D_, g2, be2, sc2, sh2);
    k_bnact<<<gD, blk, 0, stream>>>(p_a, D_, sc2, sh2);

    MF(p_a, 0, nullptr, D_, pw3_b, p_b, D_, pb3, BT, D_, D_ * 5, 2, 0, 0);
    k_stats<<<512, blk, 0, stream>>>(p_b, D_, g3, be3, sc3, sh3);
    k_bnact<<<gD, blk, 0, stream>>>(p_b, D_, sc3, sh3);

    MF(p_b, 0, nullptr, D_, pw4_b, out_post, M_, pb4, BT, M_, D_ * 5, 2, 0, 0);
    k_residual<<<4000, blk, 0, stream>>>(out_mel, out_post);
}

// Round 8
// 7457.644 us; speedup vs baseline: 3.1366x; 1.4909x over previous
//
#include <hip/hip_runtime.h>
#include <math.h>

#define B_  32
#define S_  256
#define T_  400
#define M_  80
#define D_  512
#define H_  8
#define DH  64
#define BT  (B_*T_)    // 12800
#define BS  (B_*S_)    // 8192
#define G4  (4*D_)     // 2048
#define DM  (D_+M_)    // 592
#define NB_ 32         // blocks in persistent LSTM kernel

typedef short s16x8 __attribute__((ext_vector_type(8)));
typedef float f32x4 __attribute__((ext_vector_type(4)));

__device__ __forceinline__ unsigned short f2bf(float f) {
    union { float f; unsigned u; } v; v.f = f;
    unsigned r = v.u + 0x7fffu + ((v.u >> 16) & 1u);
    return (unsigned short)(r >> 16);
}
__device__ __forceinline__ float us2f(unsigned short u) {
    union { unsigned i; float f; } v; v.i = ((unsigned)u) << 16; return v.f;
}
__device__ __forceinline__ uint4 pack8(const float* f) {
    uint4 u;
    u.x = (unsigned)f2bf(f[0]) | ((unsigned)f2bf(f[1]) << 16);
    u.y = (unsigned)f2bf(f[2]) | ((unsigned)f2bf(f[3]) << 16);
    u.z = (unsigned)f2bf(f[4]) | ((unsigned)f2bf(f[5]) << 16);
    u.w = (unsigned)f2bf(f[6]) | ((unsigned)f2bf(f[7]) << 16);
    return u;
}

// ---------------------------------------------------------------- prep: bias sums + barrier/accum zero
__global__ __launch_bounds__(256) void k_prep(
    const float* __restrict__ bih0, const float* __restrict__ bhh0,
    const float* __restrict__ bih1, const float* __restrict__ bhh1,
    float* __restrict__ bsum0, float* __restrict__ bsum1,
    int* __restrict__ bar0, int* __restrict__ bar1,
    float* __restrict__ ssum, float* __restrict__ ssq)
{
    int i = blockIdx.x * 256 + threadIdx.x;
    if (i < G4) {
        bsum0[i] = bih0[i] + bhh0[i];
        bsum1[i] = bih1[i] + bhh1[i];
    }
    if (i < 512) { ssum[i] = 0.f; ssq[i] = 0.f; }
    if (i == 0) { *bar0 = 0; *bar1 = 0; }
}

// ---------------------------------------------------------------- weight prep
__global__ __launch_bounds__(256) void k_w_c(
    const float* __restrict__ src, unsigned short* __restrict__ dst, int n)
{
    int i = blockIdx.x * 256 + threadIdx.x;
    if (i < n) dst[i] = f2bf(src[i]);
}
// transpose [K,N] fp32 -> [N,K] bf16
__global__ __launch_bounds__(256) void k_w_t(
    const float* __restrict__ src, unsigned short* __restrict__ dst, int K, int N)
{
    int i = blockIdx.x * 256 + threadIdx.x;
    if (i < K * N) {
        int n = i / K, k = i - n * K;
        dst[i] = f2bf(src[(size_t)k * N + n]);
    }
}

// ---------------------------------------------------------------- Weff = W_in@Wq, beff = b_in@Wq + bq
__global__ __launch_bounds__(256) void k_weff(
    const float* __restrict__ W_in, const float* __restrict__ Wq,
    const float* __restrict__ b_in, const float* __restrict__ bq,
    float* __restrict__ Weff, float* __restrict__ beff)
{
    int idx = blockIdx.x * 256 + threadIdx.x;
    if (idx < M_ * D_) {
        int m = idx / D_, d = idx - m * D_;
        float acc = 0.f;
        for (int j = 0; j < D_; ++j)
            acc += W_in[(size_t)m * D_ + j] * Wq[(size_t)j * D_ + d];
        Weff[idx] = acc;
    }
    if (idx < D_) {
        float acc = bq[idx];
        for (int j = 0; j < D_; ++j)
            acc += b_in[j] * Wq[(size_t)j * D_ + idx];
        beff[idx] = acc;
    }
}

// ---------------------------------------------------------------- MFMA GEMM (unchanged, verified R5/R6)
__global__ __launch_bounds__(256) void k_mfma(
    const void* __restrict__ Aptr, int lda, const float* __restrict__ mel, int srcC,
    const unsigned short* __restrict__ Bt,
    void* __restrict__ Cptr, int ldc, const float* __restrict__ bias,
    int M, int N, int K, int mode, int abf16, int cbf16)
{
    __shared__ unsigned short As[128][40];
    __shared__ unsigned short Bs[128][40];
    int tid = threadIdx.x;
    int m0 = blockIdx.x * 128, n0 = blockIdx.y * 128;
    int wave = tid >> 6, lane = tid & 63;
    int wm = (wave >> 1) * 64, wn = (wave & 1) * 64;
    int l15 = lane & 15, quad = lane >> 4;

    f32x4 acc[4][4] = {};

    int srow = tid >> 1, half = tid & 1;
    int arow = m0 + srow;
    bool mok = arow < M;
    int arc = mok ? arow : 0;

    const float* Af = (const float*)Aptr;
    const unsigned short* Ab = (const unsigned short*)Aptr;
    const float* Arow_f = nullptr; const unsigned short* Arow_b = nullptr;
    const float* Mrow = nullptr;
    int bA = 0, tA = 0;
    if (mode == 2) { bA = arc / T_; tA = arc - bA * T_; }
    else {
        if (abf16) Arow_b = Ab + (size_t)arc * lda;
        else       Arow_f = Af + (size_t)arc * lda;
        if (mode == 1) {
            int tt = arc % T_;
            if (tt > 0) Mrow = mel + (size_t)(arc - 1) * M_;
        }
    }
    int brow = n0 + srow;
    bool nok = brow < N;
    const unsigned short* Brow = Bt + (size_t)(nok ? brow : 0) * K;
    const uint4 z4 = make_uint4(0, 0, 0, 0);

    for (int k0 = 0; k0 < K; k0 += 32) {
        int ks = k0 + half * 16;
        uint4 a0, a1;
        if (!mok || ks >= K) { a0 = z4; a1 = z4; }
        else if (mode == 2) {
            float tf[16];
            #pragma unroll
            for (int i = 0; i < 16; ++i) {
                int ka = ks + i;
                int c = ka / 5, kk = ka - c * 5;
                int tt = tA + kk - 2;
                tf[i] = (tt >= 0 && tt < T_) ? Af[(size_t)(bA * T_ + tt) * srcC + c] : 0.f;
            }
            a0 = pack8(tf); a1 = pack8(tf + 8);
        } else if (abf16) {
            const uint4* s = (const uint4*)(Arow_b + ks);
            a0 = s[0]; a1 = s[1];
        } else if (mode == 1 && ks >= D_) {
            if (Mrow) {
                float tf[16];
                const float4* s = (const float4*)(Mrow + (ks - D_));
                #pragma unroll
                for (int i = 0; i < 4; ++i) {
                    float4 v = s[i];
                    tf[i*4+0] = v.x; tf[i*4+1] = v.y; tf[i*4+2] = v.z; tf[i*4+3] = v.w;
                }
                a0 = pack8(tf); a1 = pack8(tf + 8);
            } else { a0 = z4; a1 = z4; }
        } else {
            float tf[16];
            const float4* s = (const float4*)(Arow_f + ks);
            #pragma unroll
            for (int i = 0; i < 4; ++i) {
                float4 v = s[i];
                tf[i*4+0] = v.x; tf[i*4+1] = v.y; tf[i*4+2] = v.z; tf[i*4+3] = v.w;
            }
            a0 = pack8(tf); a1 = pack8(tf + 8);
        }
        *(uint4*)&As[srow][half * 16]     = a0;
        *(uint4*)&As[srow][half * 16 + 8] = a1;

        uint4 b0, b1;
        if (!nok || ks >= K) { b0 = z4; b1 = z4; }
        else {
            const uint4* s = (const uint4*)(Brow + ks);
            b0 = s[0]; b1 = s[1];
        }
        *(uint4*)&Bs[srow][half * 16]     = b0;
        *(uint4*)&Bs[srow][half * 16 + 8] = b1;
        __syncthreads();

        s16x8 af[4], bfr[4];
        #pragma unroll
        for (int i = 0; i < 4; ++i)
            af[i] = *(const s16x8*)&As[wm + i * 16 + l15][quad * 8];
        #pragma unroll
        for (int j = 0; j < 4; ++j)
            bfr[j] = *(const s16x8*)&Bs[wn + j * 16 + l15][quad * 8];
        #pragma unroll
        for (int i = 0; i < 4; ++i)
            #pragma unroll
            for (int j = 0; j < 4; ++j)
                acc[i][j] = __builtin_amdgcn_mfma_f32_16x16x32_bf16(af[i], bfr[j], acc[i][j], 0, 0, 0);
        __syncthreads();
    }

    #pragma unroll
    for (int i = 0; i < 4; ++i) {
        #pragma unroll
        for (int j = 0; j < 4; ++j) {
            int col = n0 + wn + j * 16 + l15;
            if (col >= N) continue;
            float bv = bias ? bias[col] : 0.f;
            #pragma unroll
            for (int r = 0; r < 4; ++r) {
                int row = m0 + wm + i * 16 + quad * 4 + r;
                if (row >= M) continue;
                float v = acc[i][j][r] + bv;
                if (cbf16) ((unsigned short*)Cptr)[(size_t)row * ldc + col] = f2bf(v);
                else       ((float*)Cptr)[(size_t)row * ldc + col] = v;
            }
        }
    }
}

// ---------------------------------------------------------------- attention (fp32, q on the fly)
__global__ __launch_bounds__(256) void k_attn(
    const float* __restrict__ mel,
    const float* __restrict__ Weff, const float* __restrict__ beff,
    const float* __restrict__ Kb, const float* __restrict__ Vb,
    float* __restrict__ ctx)
{
    __shared__ float mrow[4][80];
    __shared__ float qs[4][64];
    __shared__ float ps[4][256];
    int w = threadIdx.x >> 6, lane = threadIdx.x & 63;
    int row = blockIdx.x * 4 + w;
    int t = row % T_; int bh = row / T_;
    int h = bh % H_;  int b = bh / H_;

    {
        float v = 0.f;
        if (t > 0) v = mel[(size_t)(b * T_ + (t - 1)) * M_ + lane];
        mrow[w][lane] = v;
        if (lane < 16) {
            float v2 = 0.f;
            if (t > 0) v2 = mel[(size_t)(b * T_ + (t - 1)) * M_ + 64 + lane];
            mrow[w][64 + lane] = v2;
        }
    }
    __syncthreads();
    {
        int d = h * DH + lane;
        float q = beff[d];
        #pragma unroll 8
        for (int m = 0; m < M_; ++m) q += mrow[w][m] * Weff[(size_t)m * D_ + d];
        qs[w][lane] = q;
    }
    __syncthreads();

    const float* Kbase = Kb + (size_t)(b * S_) * D_ + h * DH;
    float sc[4];
    #pragma unroll
    for (int i = 0; i < 4; ++i) {
        int s = lane + i * 64;
        const float4* kr = (const float4*)(Kbase + (size_t)s * D_);
        float acc = 0.f;
        #pragma unroll
        for (int c4 = 0; c4 < 16; ++c4) {
            float4 kv = kr[c4];
            acc += qs[w][c4 * 4 + 0] * kv.x + qs[w][c4 * 4 + 1] * kv.y
                 + qs[w][c4 * 4 + 2] * kv.z + qs[w][c4 * 4 + 3] * kv.w;
        }
        sc[i] = acc * 0.125f;
    }
    float mx = fmaxf(fmaxf(sc[0], sc[1]), fmaxf(sc[2], sc[3]));
    #pragma unroll
    for (int off = 32; off; off >>= 1) mx = fmaxf(mx, __shfl_xor(mx, off, 64));
    float sum = 0.f;
    #pragma unroll
    for (int i = 0; i < 4; ++i) { sc[i] = __expf(sc[i] - mx); sum += sc[i]; }
    #pragma unroll
    for (int off = 32; off; off >>= 1) sum += __shfl_xor(sum, off, 64);
    float inv = 1.f / sum;
    #pragma unroll
    for (int i = 0; i < 4; ++i) ps[w][lane + i * 64] = sc[i] * inv;
    __syncthreads();

    const float* Vbase = Vb + (size_t)(b * S_) * D_ + h * DH + lane;
    float acc = 0.f;
    for (int s = 0; s < S_; ++s) acc += ps[w][s] * Vbase[(size_t)s * D_];
    ctx[(size_t)(b * T_ + t) * D_ + h * DH + lane] = acc;
}

// ---------------------------------------------------------------- persistent LSTM layer, coalesced
// 32 blocks; block bd owns 16 contiguous dims d0=bd*16 (64 Whh rows in LDS).
// Pad = 520 cols: row stride 1040 B == 0 mod 16 (b128 alignment) — do NOT change.
__global__ __launch_bounds__(256) void k_lstm_coop(
    const unsigned short* __restrict__ xg,    // [B,T,2048] bf16 (biases folded)
    const unsigned short* __restrict__ Whh,   // [2048,512] bf16
    unsigned short* __restrict__ hseq,        // [B,T,512] bf16 out
    unsigned short* __restrict__ hpp,         // [2][32*512] bf16 ping-pong
    int* __restrict__ bar)
{
    __shared__ unsigned short Ws[64][520];    // row r = g*16+d
    __shared__ unsigned short hs[32][520];    // staged h_{t-1}, row = batch
    __shared__ float gl[64][33];              // gates
    __shared__ unsigned short hout[32][16];   // this block's h slice
    int tid = threadIdx.x;
    int d0 = blockIdx.x * 16;

    { // load Whh slice: 64 rows x 512 bf16; 4 threads/row x 128 elems (16 x uint4)
        int r = tid >> 2, seg = tid & 3;
        int g = r >> 4, d = r & 15;
        const uint4* src = (const uint4*)(Whh + ((size_t)(g * 512 + d0 + d) * 512) + seg * 128);
        uint4* dst = (uint4*)&Ws[r][seg * 128];
        #pragma unroll
        for (int j = 0; j < 16; ++j) dst[j] = src[j];
    }
    int lane = tid & 63, wv = tid >> 6;
    int l15 = lane & 15, quad = lane >> 4;
    int b_u = tid >> 3, dp = tid & 7;         // update: batch, dim-pair (dims 2dp, 2dp+1)
    float c0r = 0.f, c1r = 0.f;
    __syncthreads();

    for (int t = 0; t < T_; ++t) {
        // coalesced xg loads: 4 gates x 1 dword (2 bf16)
        unsigned xv[4];
        {
            const unsigned short* xr = xg + ((size_t)(b_u * T_ + t) * G4) + d0 + 2 * dp;
            #pragma unroll
            for (int g = 0; g < 4; ++g) xv[g] = *(const unsigned*)(xr + g * 512);
        }
        if (t > 0) {
            // stage h_{t-1}: 32 KB fully coalesced
            const uint4* hrd = (const uint4*)(hpp + ((t + 1) & 1) * (32 * 512));
            #pragma unroll
            for (int i = 0; i < 8; ++i) {
                int u = i * 256 + tid;            // 16B unit
                int row = u >> 6, col = u & 63;
                *(uint4*)&hs[row][col * 8] = hrd[u];
            }
            __syncthreads();
            f32x4 acc0 = {}, acc1 = {};
            #pragma unroll
            for (int k0 = 0; k0 < 512; k0 += 32) {
                s16x8 af = *(const s16x8*)&Ws[wv * 16 + l15][k0 + quad * 8];
                s16x8 b0 = *(const s16x8*)&hs[l15][k0 + quad * 8];
                s16x8 b1 = *(const s16x8*)&hs[16 + l15][k0 + quad * 8];
                acc0 = __builtin_amdgcn_mfma_f32_16x16x32_bf16(af, b0, acc0, 0, 0, 0);
                acc1 = __builtin_amdgcn_mfma_f32_16x16x32_bf16(af, b1, acc1, 0, 0, 0);
            }
            #pragma unroll
            for (int r = 0; r < 4; ++r) {
                gl[wv * 16 + quad * 4 + r][l15]      = acc0[r];
                gl[wv * 16 + quad * 4 + r][16 + l15] = acc1[r];
            }
        }
        __syncthreads();
        { // update two dims
            float h2v[2];
            #pragma unroll
            for (int q = 0; q < 2; ++q) {
                int d = 2 * dp + q;
                float iv = us2f((unsigned short)(xv[0] >> (16 * q)));
                float fv = us2f((unsigned short)(xv[1] >> (16 * q)));
                float gv = us2f((unsigned short)(xv[2] >> (16 * q)));
                float ov = us2f((unsigned short)(xv[3] >> (16 * q)));
                if (t > 0) {
                    iv += gl[0 * 16 + d][b_u];
                    fv += gl[1 * 16 + d][b_u];
                    gv += gl[2 * 16 + d][b_u];
                    ov += gl[3 * 16 + d][b_u];
                }
                float si = 1.f / (1.f + __expf(-iv));
                float sf = 1.f / (1.f + __expf(-fv));
                float so = 1.f / (1.f + __expf(-ov));
                float tg = tanhf(gv);
                float cold = (t > 0) ? (q ? c1r : c0r) : 0.f;
                float c = sf * cold + si * tg;
                float h = so * tanhf(c);
                if (q) c1r = c; else c0r = c;
                h2v[q] = h;
            }
            unsigned pk = (unsigned)f2bf(h2v[0]) | ((unsigned)f2bf(h2v[1]) << 16);
            *(unsigned*)&hout[b_u][2 * dp] = pk;
        }
        __syncthreads();
        if (tid < 64) {
            int b = tid >> 1, half = tid & 1;
            uint4 v = *(const uint4*)&hout[b][half * 8];
            *(uint4*)(hpp + (t & 1) * (32 * 512) + (size_t)b * 512 + d0 + half * 8) = v;
            *(uint4*)(hseq + ((size_t)b * T_ + t) * 512 + d0 + half * 8) = v;
        }
        __syncthreads();
        if (tid == 0) {
            __threadfence();
            __hip_atomic_fetch_add(bar, 1, __ATOMIC_RELEASE, __HIP_MEMORY_SCOPE_AGENT);
            int target = NB_ * (t + 1);
            while (__hip_atomic_load(bar, __ATOMIC_RELAXED, __HIP_MEMORY_SCOPE_AGENT) < target)
                __builtin_amdgcn_s_sleep(1);
            __threadfence();
        }
        __syncthreads();
    }
}

// ---------------------------------------------------------------- stop head
__global__ __launch_bounds__(256) void k_stop(
    const unsigned short* __restrict__ h2, const float* __restrict__ W,
    const float* __restrict__ bsc, float* __restrict__ out)
{
    int w = threadIdx.x >> 6, lane = threadIdx.x & 63;
    int row = blockIdx.x * 4 + w;
    const unsigned short* hr = h2 + (size_t)row * 512 + lane * 8;
    float acc = 0.f;
    #pragma unroll
    for (int j = 0; j < 8; ++j) acc += us2f(hr[j]) * W[lane * 8 + j];
    #pragma unroll
    for (int off = 32; off; off >>= 1) acc += __shfl_xor(acc, off, 64);
    if (lane == 0) out[row] = acc + bsc[0];
}

// ---------------------------------------------------------------- BN stats: coalesced partial + atomic
__global__ __launch_bounds__(256) void k_stats_part(
    const float* __restrict__ x, float* __restrict__ ssum, float* __restrict__ ssq)
{
    int r0 = blockIdx.x * 50;
    int c1 = threadIdx.x, c2 = threadIdx.x + 256;
    float s1 = 0.f, q1 = 0.f, s2 = 0.f, q2 = 0.f;
    for (int r = r0; r < r0 + 50; ++r) {
        float v1 = x[(size_t)r * 512 + c1]; s1 += v1; q1 += v1 * v1;
        float v2 = x[(size_t)r * 512 + c2]; s2 += v2; q2 += v2 * v2;
    }
    atomicAdd(&ssum[c1], s1); atomicAdd(&ssq[c1], q1);
    atomicAdd(&ssum[c2], s2); atomicAdd(&ssq[c2], q2);
}
// finalize + re-zero accumulators for next use
__global__ __launch_bounds__(256) void k_stats_fin(
    float* __restrict__ ssum, float* __restrict__ ssq,
    const float* __restrict__ gw, const float* __restrict__ bw,
    float* __restrict__ scale, float* __restrict__ shift)
{
    int c = blockIdx.x * 256 + threadIdx.x;
    if (c < 512) {
        float mean = ssum[c] / (float)BT;
        float var  = ssq[c] / (float)BT - mean * mean;
        float scv  = gw[c] * rsqrtf(var + 1e-5f);
        scale[c] = scv;
        shift[c] = bw[c] - mean * scv;
        ssum[c] = 0.f; ssq[c] = 0.f;
    }
}

__global__ __launch_bounds__(256) void k_bnact(
    float* __restrict__ x, int C,
    const float* __restrict__ scale, const float* __restrict__ shift)
{
    int idx = blockIdx.x * 256 + threadIdx.x;
    if (idx < BT * C) {
        int c = idx % C;
        x[idx] = tanhf(scale[c] * x[idx] + shift[c]);
    }
}

__global__ __launch_bounds__(256) void k_residual(
    const float* __restrict__ mel, float* __restrict__ out)
{
    int i = blockIdx.x * 256 + threadIdx.x;
    if (i < BT * M_) out[i] += mel[i];
}

// ================================================================ launch
extern "C" void kernel_launch(void* const* d_in, const int* in_sizes, int n_in,
                              void* d_out, int out_size, void* d_ws, size_t ws_size,
                              hipStream_t stream)
{
    const float* enc    = (const float*)d_in[0];
    const float* mel_t  = (const float*)d_in[1];
    const float* W_in   = (const float*)d_in[2];
    const float* b_in   = (const float*)d_in[3];
    const float* Wq     = (const float*)d_in[4];  const float* bq = (const float*)d_in[5];
    const float* Wk     = (const float*)d_in[6];  const float* bk = (const float*)d_in[7];
    const float* Wv     = (const float*)d_in[8];  const float* bv = (const float*)d_in[9];
    const float* Wo     = (const float*)d_in[10]; const float* bo = (const float*)d_in[11];
    const float* W_ih0  = (const float*)d_in[12]; const float* W_hh0 = (const float*)d_in[13];
    const float* b_ih0  = (const float*)d_in[14]; const float* b_hh0 = (const float*)d_in[15];
    const float* W_ih1  = (const float*)d_in[16]; const float* W_hh1 = (const float*)d_in[17];
    const float* b_ih1  = (const float*)d_in[18]; const float* b_hh1 = (const float*)d_in[19];
    const float* W_mel  = (const float*)d_in[20]; const float* b_mel = (const float*)d_in[21];
    const float* W_stop = (const float*)d_in[22]; const float* b_stop = (const float*)d_in[23];
    const float* pw0 = (const float*)d_in[24]; const float* pb0 = (const float*)d_in[25];
    const float* pw1 = (const float*)d_in[26]; const float* pb1 = (const float*)d_in[27];
    const float* pw2 = (const float*)d_in[28]; const float* pb2 = (const float*)d_in[29];
    const float* pw3 = (const float*)d_in[30]; const float* pb3 = (const float*)d_in[31];
    const float* pw4 = (const float*)d_in[32]; const float* pb4 = (const float*)d_in[33];
    const float* g0 = (const float*)d_in[34]; const float* be0 = (const float*)d_in[35];
    const float* g1 = (const float*)d_in[36]; const float* be1 = (const float*)d_in[37];
    const float* g2 = (const float*)d_in[38]; const float* be2 = (const float*)d_in[39];
    const float* g3 = (const float*)d_in[40]; const float* be3 = (const float*)d_in[41];

    char* p = (char*)d_ws;
    float* Kb  = (float*)(p + 0);
    float* Vb  = (float*)(p + 16777216);
    float* ctx = (float*)(p + 33554432);
    float* ao  = (float*)(p + 0);
    unsigned short* xg0   = (unsigned short*)(p + 26214400);
    unsigned short* h1seq = (unsigned short*)(p + 0);
    unsigned short* xg1   = (unsigned short*)(p + 13107200);
    unsigned short* h2seq = (unsigned short*)(p + 65536000);
    float* p_a = (float*)(p + 0);
    float* p_b = (float*)(p + 26214400);
    size_t off = 78643200;
    float* bsum0 = (float*)(p + off); off += 8192;
    float* bsum1 = (float*)(p + off); off += 8192;
    unsigned short* hpp = (unsigned short*)(p + off); off += 65536;
    float* beff = (float*)(p + off); off += 2048;
    float* Weff = (float*)(p + off); off += 163840;
    float* sc0 = (float*)(p + off); off += 2048;
    float* sh0 = (float*)(p + off); off += 2048;
    float* sc1 = (float*)(p + off); off += 2048;
    float* sh1 = (float*)(p + off); off += 2048;
    float* sc2 = (float*)(p + off); off += 2048;
    float* sh2 = (float*)(p + off); off += 2048;
    float* sc3 = (float*)(p + off); off += 2048;
    float* sh3 = (float*)(p + off); off += 2048;
    float* ssum = (float*)(p + off); off += 2048;
    float* ssq  = (float*)(p + off); off += 2048;
    int* bar0 = (int*)(p + off); off += 128;
    int* bar1 = (int*)(p + off); off += 128;
    unsigned short* Wk_t   = (unsigned short*)(p + off); off += 524288;
    unsigned short* Wv_t   = (unsigned short*)(p + off); off += 524288;
    unsigned short* Wo_t   = (unsigned short*)(p + off); off += 524288;
    unsigned short* Wmel_t = (unsigned short*)(p + off); off += 81920;
    unsigned short* Wih0_b = (unsigned short*)(p + off); off += 2424832;
    unsigned short* Wih1_b = (unsigned short*)(p + off); off += 2097152;
    unsigned short* Whh0_b = (unsigned short*)(p + off); off += 2097152;
    unsigned short* Whh1_b = (unsigned short*)(p + off); off += 2097152;
    unsigned short* pw0_b  = (unsigned short*)(p + off); off += 409600;
    unsigned short* pw1_b  = (unsigned short*)(p + off); off += 2621440;
    unsigned short* pw2_b  = (unsigned short*)(p + off); off += 2621440;
    unsigned short* pw3_b  = (unsigned short*)(p + off); off += 2621440;
    unsigned short* pw4_b  = (unsigned short*)(p + off); off += 409600;

    float* out_mel  = (float*)d_out;
    float* out_post = out_mel + (size_t)BT * M_;
    float* out_stop = out_post + (size_t)BT * M_;

    dim3 blk(256);
    auto MF = [&](const void* A, int lda, const float* mel, int srcC,
                  const unsigned short* Bt, void* C, int ldc, const float* bias,
                  int M, int N, int K, int mode, int abf16, int cbf16) {
        dim3 g((M + 127) / 128, (N + 127) / 128);
        k_mfma<<<g, blk, 0, stream>>>(A, lda, mel, srcC, Bt, C, ldc, bias, M, N, K, mode, abf16, cbf16);
    };

    // ---- prep
    k_prep<<<8, blk, 0, stream>>>(b_ih0, b_hh0, b_ih1, b_hh1, bsum0, bsum1, bar0, bar1, ssum, ssq);
    k_weff<<<160, blk, 0, stream>>>(W_in, Wq, b_in, bq, Weff, beff);
    k_w_t<<<1024, blk, 0, stream>>>(Wk, Wk_t, D_, D_);
    k_w_t<<<1024, blk, 0, stream>>>(Wv, Wv_t, D_, D_);
    k_w_t<<<1024, blk, 0, stream>>>(Wo, Wo_t, D_, D_);
    k_w_t<<<160, blk, 0, stream>>>(W_mel, Wmel_t, D_, M_);
    k_w_c<<<4736, blk, 0, stream>>>(W_ih0, Wih0_b, G4 * DM);
    k_w_c<<<4096, blk, 0, stream>>>(W_ih1, Wih1_b, G4 * D_);
    k_w_c<<<4096, blk, 0, stream>>>(W_hh0, Whh0_b, G4 * D_);
    k_w_c<<<4096, blk, 0, stream>>>(W_hh1, Whh1_b, G4 * D_);
    k_w_c<<<800, blk, 0, stream>>>(pw0, pw0_b, 512 * 400);
    k_w_c<<<5120, blk, 0, stream>>>(pw1, pw1_b, 512 * 2560);
    k_w_c<<<5120, blk, 0, stream>>>(pw2, pw2_b, 512 * 2560);
    k_w_c<<<5120, blk, 0, stream>>>(pw3, pw3_b, 512 * 2560);
    k_w_c<<<800, blk, 0, stream>>>(pw4, pw4_b, 80 * 2560);

    // ---- K/V projections
    MF(enc, D_, nullptr, 0, Wk_t, Kb, D_, bk, BS, D_, D_, 0, 0, 0);
    MF(enc, D_, nullptr, 0, Wv_t, Vb, D_, bv, BS, D_, D_, 0, 0, 0);

    // ---- attention
    k_attn<<<(B_ * H_ * T_) / 4, blk, 0, stream>>>(mel_t, Weff, beff, Kb, Vb, ctx);

    // ---- attn_out = ctx @ Wo + bo
    MF(ctx, D_, nullptr, 0, Wo_t, ao, D_, bo, BT, D_, D_, 0, 0, 0);

    // ---- xg0 (full T, bf16 out, virtual [ao | dec_in] concat, K=592)
    MF(ao, D_, mel_t, 0, Wih0_b, xg0, G4, bsum0, BT, G4, DM, 1, 0, 1);

    // ---- LSTM layer 0
    k_lstm_coop<<<NB_, blk, 0, stream>>>(xg0, Whh0_b, h1seq, hpp, bar0);

    // ---- xg1 = h1seq(bf16) @ W_ih1^T + bsum1
    MF(h1seq, D_, nullptr, 0, Wih1_b, xg1, G4, bsum1, BT, G4, D_, 0, 1, 1);

    // ---- LSTM layer 1
    k_lstm_coop<<<NB_, blk, 0, stream>>>(xg1, Whh1_b, h2seq, hpp, bar1);

    // ---- heads
    MF(h2seq, D_, nullptr, 0, Wmel_t, out_mel, M_, b_mel, BT, M_, D_, 0, 1, 0);
    k_stop<<<BT / 4, blk, 0, stream>>>(h2seq, W_stop, b_stop, out_stop);

    // ---- postnet
    int gD = (BT * D_ + 255) / 256;

    MF(out_mel, 0, nullptr, M_, pw0_b, p_a, D_, pb0, BT, D_, M_ * 5, 2, 0, 0);
    k_stats_part<<<256, blk, 0, stream>>>(p_a, ssum, ssq);
    k_stats_fin<<<2, blk, 0, stream>>>(ssum, ssq, g0, be0, sc0, sh0);
    k_bnact<<<gD, blk, 0, stream>>>(p_a, D_, sc0, sh0);

    MF(p_a, 0, nullptr, D_, pw1_b, p_b, D_, pb1, BT, D_, D_ * 5, 2, 0, 0);
    k_stats_part<<<256, blk, 0, stream>>>(p_b, ssum, ssq);
    k_stats_fin<<<2, blk, 0, stream>>>(ssum, ssq, g1, be1, sc1, sh1);
    k_bnact<<<gD, blk, 0, stream>>>(p_b, D_, sc1, sh1);

    MF(p_b, 0, nullptr, D_, pw2_b, p_a, D_, pb2, BT, D_, D_ * 5, 2, 0, 0);
    k_stats_part<<<256, blk, 0, stream>>>(p_a, ssum, ssq);
    k_stats_fin<<<2, blk, 0, stream>>>(ssum, ssq, g2, be2, sc2, sh2);
    k_bnact<<<gD, blk, 0, stream>>>(p_a, D_, sc2, sh2);

    MF(p_a, 0, nullptr, D_, pw3_b, p_b, D_, pb3, BT, D_, D_ * 5, 2, 0, 0);
    k_stats_part<<<256, blk, 0, stream>>>(p_b, ssum, ssq);
    k_stats_fin<<<2, blk, 0, stream>>>(ssum, ssq, g3, be3, sc3, sh3);
    k_bnact<<<gD, blk, 0, stream>>>(p_b, D_, sc3, sh3);

    MF(p_b, 0, nullptr, D_, pw4_b, out_post, M_, pb4, BT, M_, D_ * 5, 2, 0, 0);
    k_residual<<<4000, blk, 0, stream>>>(out_mel, out_post);
}

// Round 9
// 5837.873 us; speedup vs baseline: 4.0069x; 1.2775x over previous
//
#include <hip/hip_runtime.h>
#include <math.h>

#define B_  32
#define S_  256
#define T_  400
#define M_  80
#define D_  512
#define H_  8
#define DH  64
#define BT  (B_*T_)    // 12800
#define BS  (B_*S_)    // 8192
#define G4  (4*D_)     // 2048
#define DM  (D_+M_)    // 592
#define NB_ 96         // persistent blocks: 32 L0 + 64 L1

typedef short s16x8 __attribute__((ext_vector_type(8)));
typedef float f32x4 __attribute__((ext_vector_type(4)));

__device__ __forceinline__ unsigned short f2bf(float f) {
    union { float f; unsigned u; } v; v.f = f;
    unsigned r = v.u + 0x7fffu + ((v.u >> 16) & 1u);
    return (unsigned short)(r >> 16);
}
__device__ __forceinline__ float us2f(unsigned short u) {
    union { unsigned i; float f; } v; v.i = ((unsigned)u) << 16; return v.f;
}
__device__ __forceinline__ uint4 pack8(const float* f) {
    uint4 u;
    u.x = (unsigned)f2bf(f[0]) | ((unsigned)f2bf(f[1]) << 16);
    u.y = (unsigned)f2bf(f[2]) | ((unsigned)f2bf(f[3]) << 16);
    u.z = (unsigned)f2bf(f[4]) | ((unsigned)f2bf(f[5]) << 16);
    u.w = (unsigned)f2bf(f[6]) | ((unsigned)f2bf(f[7]) << 16);
    return u;
}

// ---------------------------------------------------------------- prep: bias sums, flag/hx2/accum zero
__global__ __launch_bounds__(256) void k_prep(
    const float* __restrict__ bih0, const float* __restrict__ bhh0,
    const float* __restrict__ bih1, const float* __restrict__ bhh1,
    float* __restrict__ bsum0, float* __restrict__ bsum1,
    int* __restrict__ flags, int* __restrict__ hx2i,
    float* __restrict__ ssum, float* __restrict__ ssq)
{
    int i = blockIdx.x * 256 + threadIdx.x;
    if (i < G4) {
        bsum0[i] = bih0[i] + bhh0[i];
        bsum1[i] = bih1[i] + bhh1[i];
    }
    if (i < 512) { ssum[i] = 0.f; ssq[i] = 0.f; }
    if (i < NB_ * 32) flags[i] = 0;
    if (i < 2 * 32 * 512 / 2) hx2i[i] = 0;   // both hx2 buffers (bf16 pairs as ints)
}

// ---------------------------------------------------------------- batched weight prep
// plain fp32->bf16 copies (4 tensors)
__global__ __launch_bounds__(256) void k_w_c4(
    const float* s0, unsigned short* d0p, int n0,
    const float* s1, unsigned short* d1p, int n1,
    const float* s2, unsigned short* d2p, int n2,
    const float* s3, unsigned short* d3p, int n3)
{
    const float* s; unsigned short* d; int n;
    switch (blockIdx.y) {
        case 0: s = s0; d = d0p; n = n0; break;
        case 1: s = s1; d = d1p; n = n1; break;
        case 2: s = s2; d = d2p; n = n2; break;
        default: s = s3; d = d3p; n = n3; break;
    }
    int i = blockIdx.x * 256 + threadIdx.x;
    if (i < n) d[i] = f2bf(s[i]);
}
// transposes [K,N] fp32 -> [N,K] bf16 (4 tensors)
__global__ __launch_bounds__(256) void k_w_t4(
    const float* s0, unsigned short* d0p, int K0, int N0,
    const float* s1, unsigned short* d1p, int K1, int N1,
    const float* s2, unsigned short* d2p, int K2, int N2,
    const float* s3, unsigned short* d3p, int K3, int N3)
{
    const float* s; unsigned short* d; int K, N;
    switch (blockIdx.y) {
        case 0: s = s0; d = d0p; K = K0; N = N0; break;
        case 1: s = s1; d = d1p; K = K1; N = N1; break;
        case 2: s = s2; d = d2p; K = K2; N = N2; break;
        default: s = s3; d = d3p; K = K3; N = N3; break;
    }
    int i = blockIdx.x * 256 + threadIdx.x;
    if (i < K * N) {
        int n = i / K, k = i - n * K;
        d[i] = f2bf(s[(size_t)k * N + n]);
    }
}
// conv weight permute: src [O][C*5] (c-major,k-minor) -> dst [O][5*C] (k-major,c-minor), bf16
__global__ __launch_bounds__(256) void k_w_conv5(
    const float* s0, unsigned short* d0p, int O0, int C0,
    const float* s1, unsigned short* d1p, int O1, int C1,
    const float* s2, unsigned short* d2p, int O2, int C2,
    const float* s3, unsigned short* d3p, int O3, int C3,
    const float* s4, unsigned short* d4p, int O4, int C4)
{
    const float* s; unsigned short* d; int O, C;
    switch (blockIdx.y) {
        case 0: s = s0; d = d0p; O = O0; C = C0; break;
        case 1: s = s1; d = d1p; O = O1; C = C1; break;
        case 2: s = s2; d = d2p; O = O2; C = C2; break;
        case 3: s = s3; d = d3p; O = O3; C = C3; break;
        default: s = s4; d = d4p; O = O4; C = C4; break;
    }
    int i = blockIdx.x * 256 + threadIdx.x;
    int n = O * C * 5;
    if (i < n) {
        int o = i / (5 * C), rem = i - o * 5 * C;
        int k = rem / C, c = rem - k * C;
        d[i] = f2bf(s[(size_t)o * C * 5 + c * 5 + k]);
    }
}

// ---------------------------------------------------------------- Weff = W_in@Wq, beff = b_in@Wq + bq
__global__ __launch_bounds__(256) void k_weff(
    const float* __restrict__ W_in, const float* __restrict__ Wq,
    const float* __restrict__ b_in, const float* __restrict__ bq,
    float* __restrict__ Weff, float* __restrict__ beff)
{
    int idx = blockIdx.x * 256 + threadIdx.x;
    if (idx < M_ * D_) {
        int m = idx / D_, d = idx - m * D_;
        float acc = 0.f;
        for (int j = 0; j < D_; ++j)
            acc += W_in[(size_t)m * D_ + j] * Wq[(size_t)j * D_ + d];
        Weff[idx] = acc;
    }
    if (idx < D_) {
        float acc = bq[idx];
        for (int j = 0; j < D_; ++j)
            acc += b_in[j] * Wq[(size_t)j * D_ + idx];
        beff[idx] = acc;
    }
}

// ---------------------------------------------------------------- MFMA GEMM
// mode 0: A row m = A[m,:] (lda), fp32 or bf16
// mode 1: A row m=bt: [A[bt,0:512] fp32 | mel[bt-1,0:80] or 0] (K=592)
// mode 2: conv, K ordered (tap sg major, channel minor): k -> (sg=k/srcC, c=k%srcC):
//         A[bA*T + tA+sg-2, c] — contiguous vector loads per 16-block (srcC % 16 == 0)
__global__ __launch_bounds__(256) void k_mfma(
    const void* __restrict__ Aptr, int lda, const float* __restrict__ mel, int srcC,
    const unsigned short* __restrict__ Bt,
    void* __restrict__ Cptr, int ldc, const float* __restrict__ bias,
    int M, int N, int K, int mode, int abf16, int cbf16)
{
    __shared__ unsigned short As[128][40];
    __shared__ unsigned short Bs[128][40];
    int tid = threadIdx.x;
    int m0 = blockIdx.x * 128, n0 = blockIdx.y * 128;
    int wave = tid >> 6, lane = tid & 63;
    int wm = (wave >> 1) * 64, wn = (wave & 1) * 64;
    int l15 = lane & 15, quad = lane >> 4;

    f32x4 acc[4][4] = {};

    int srow = tid >> 1, half = tid & 1;
    int arow = m0 + srow;
    bool mok = arow < M;
    int arc = mok ? arow : 0;

    const float* Af = (const float*)Aptr;
    const unsigned short* Ab = (const unsigned short*)Aptr;
    const float* Arow_f = nullptr; const unsigned short* Arow_b = nullptr;
    const float* Mrow = nullptr;
    int bA = 0, tA = 0;
    if (mode == 2) { bA = arc / T_; tA = arc - bA * T_; }
    else {
        if (abf16) Arow_b = Ab + (size_t)arc * lda;
        else       Arow_f = Af + (size_t)arc * lda;
        if (mode == 1) {
            int tt = arc % T_;
            if (tt > 0) Mrow = mel + (size_t)(arc - 1) * M_;
        }
    }
    int brow = n0 + srow;
    bool nok = brow < N;
    const unsigned short* Brow = Bt + (size_t)(nok ? brow : 0) * K;
    const uint4 z4 = make_uint4(0, 0, 0, 0);

    for (int k0 = 0; k0 < K; k0 += 32) {
        int ks = k0 + half * 16;
        uint4 a0, a1;
        if (!mok || ks >= K) { a0 = z4; a1 = z4; }
        else if (mode == 2) {
            int sg = ks / srcC;
            int cc = ks - sg * srcC;
            int tt = tA + sg - 2;
            if (tt >= 0 && tt < T_) {
                float tf[16];
                const float4* s = (const float4*)(Af + (size_t)(bA * T_ + tt) * srcC + cc);
                #pragma unroll
                for (int i = 0; i < 4; ++i) {
                    float4 v = s[i];
                    tf[i*4+0] = v.x; tf[i*4+1] = v.y; tf[i*4+2] = v.z; tf[i*4+3] = v.w;
                }
                a0 = pack8(tf); a1 = pack8(tf + 8);
            } else { a0 = z4; a1 = z4; }
        } else if (abf16) {
            const uint4* s = (const uint4*)(Arow_b + ks);
            a0 = s[0]; a1 = s[1];
        } else if (mode == 1 && ks >= D_) {
            if (Mrow) {
                float tf[16];
                const float4* s = (const float4*)(Mrow + (ks - D_));
                #pragma unroll
                for (int i = 0; i < 4; ++i) {
                    float4 v = s[i];
                    tf[i*4+0] = v.x; tf[i*4+1] = v.y; tf[i*4+2] = v.z; tf[i*4+3] = v.w;
                }
                a0 = pack8(tf); a1 = pack8(tf + 8);
            } else { a0 = z4; a1 = z4; }
        } else {
            float tf[16];
            const float4* s = (const float4*)(Arow_f + ks);
            #pragma unroll
            for (int i = 0; i < 4; ++i) {
                float4 v = s[i];
                tf[i*4+0] = v.x; tf[i*4+1] = v.y; tf[i*4+2] = v.z; tf[i*4+3] = v.w;
            }
            a0 = pack8(tf); a1 = pack8(tf + 8);
        }
        *(uint4*)&As[srow][half * 16]     = a0;
        *(uint4*)&As[srow][half * 16 + 8] = a1;

        uint4 b0, b1;
        if (!nok || ks >= K) { b0 = z4; b1 = z4; }
        else {
            const uint4* s = (const uint4*)(Brow + ks);
            b0 = s[0]; b1 = s[1];
        }
        *(uint4*)&Bs[srow][half * 16]     = b0;
        *(uint4*)&Bs[srow][half * 16 + 8] = b1;
        __syncthreads();

        s16x8 af[4], bfr[4];
        #pragma unroll
        for (int i = 0; i < 4; ++i)
            af[i] = *(const s16x8*)&As[wm + i * 16 + l15][quad * 8];
        #pragma unroll
        for (int j = 0; j < 4; ++j)
            bfr[j] = *(const s16x8*)&Bs[wn + j * 16 + l15][quad * 8];
        #pragma unroll
        for (int i = 0; i < 4; ++i)
            #pragma unroll
            for (int j = 0; j < 4; ++j)
                acc[i][j] = __builtin_amdgcn_mfma_f32_16x16x32_bf16(af[i], bfr[j], acc[i][j], 0, 0, 0);
        __syncthreads();
    }

    #pragma unroll
    for (int i = 0; i < 4; ++i) {
        #pragma unroll
        for (int j = 0; j < 4; ++j) {
            int col = n0 + wn + j * 16 + l15;
            if (col >= N) continue;
            float bv = bias ? bias[col] : 0.f;
            #pragma unroll
            for (int r = 0; r < 4; ++r) {
                int row = m0 + wm + i * 16 + quad * 4 + r;
                if (row >= M) continue;
                float v = acc[i][j][r] + bv;
                if (cbf16) ((unsigned short*)Cptr)[(size_t)row * ldc + col] = f2bf(v);
                else       ((float*)Cptr)[(size_t)row * ldc + col] = v;
            }
        }
    }
}

// ---------------------------------------------------------------- attention (fp32, q on the fly)
__global__ __launch_bounds__(256) void k_attn(
    const float* __restrict__ mel,
    const float* __restrict__ Weff, const float* __restrict__ beff,
    const float* __restrict__ Kb, const float* __restrict__ Vb,
    float* __restrict__ ctx)
{
    __shared__ float mrow[4][80];
    __shared__ float qs[4][64];
    __shared__ float ps[4][256];
    int w = threadIdx.x >> 6, lane = threadIdx.x & 63;
    int row = blockIdx.x * 4 + w;
    int t = row % T_; int bh = row / T_;
    int h = bh % H_;  int b = bh / H_;

    {
        float v = 0.f;
        if (t > 0) v = mel[(size_t)(b * T_ + (t - 1)) * M_ + lane];
        mrow[w][lane] = v;
        if (lane < 16) {
            float v2 = 0.f;
            if (t > 0) v2 = mel[(size_t)(b * T_ + (t - 1)) * M_ + 64 + lane];
            mrow[w][64 + lane] = v2;
        }
    }
    __syncthreads();
    {
        int d = h * DH + lane;
        float q = beff[d];
        #pragma unroll 8
        for (int m = 0; m < M_; ++m) q += mrow[w][m] * Weff[(size_t)m * D_ + d];
        qs[w][lane] = q;
    }
    __syncthreads();

    const float* Kbase = Kb + (size_t)(b * S_) * D_ + h * DH;
    float sc[4];
    #pragma unroll
    for (int i = 0; i < 4; ++i) {
        int s = lane + i * 64;
        const float4* kr = (const float4*)(Kbase + (size_t)s * D_);
        float acc = 0.f;
        #pragma unroll
        for (int c4 = 0; c4 < 16; ++c4) {
            float4 kv = kr[c4];
            acc += qs[w][c4 * 4 + 0] * kv.x + qs[w][c4 * 4 + 1] * kv.y
                 + qs[w][c4 * 4 + 2] * kv.z + qs[w][c4 * 4 + 3] * kv.w;
        }
        sc[i] = acc * 0.125f;
    }
    float mx = fmaxf(fmaxf(sc[0], sc[1]), fmaxf(sc[2], sc[3]));
    #pragma unroll
    for (int off = 32; off; off >>= 1) mx = fmaxf(mx, __shfl_xor(mx, off, 64));
    float sum = 0.f;
    #pragma unroll
    for (int i = 0; i < 4; ++i) { sc[i] = __expf(sc[i] - mx); sum += sc[i]; }
    #pragma unroll
    for (int off = 32; off; off >>= 1) sum += __shfl_xor(sum, off, 64);
    float inv = 1.f / sum;
    #pragma unroll
    for (int i = 0; i < 4; ++i) ps[w][lane + i * 64] = sc[i] * inv;
    __syncthreads();

    const float* Vbase = Vb + (size_t)(b * S_) * D_ + h * DH + lane;
    float acc = 0.f;
    for (int s = 0; s < S_; ++s) acc += ps[w][s] * Vbase[(size_t)s * D_];
    ctx[(size_t)(b * T_ + t) * D_ + h * DH + lane] = acc;
}

// ---------------------------------------------------------------- fused 2-layer pipelined LSTM
// 96 blocks: bid<32 = L0 (16 dims, K=512, xg0 precomputed); bid>=32 = L1 (8 dims, K=1024
// fused [W_ih1|W_hh1]·[h1[t]|h2[t-1]]). Interval i: L0 -> h1[i] (i<400); L1 -> h2[i-1] (i>=1).
// Per-block arrival-flag barrier after intervals 0..399. LDS pads keep row stride % 16B == 0.
__global__ __launch_bounds__(256) void k_lstm2(
    const unsigned short* __restrict__ xg0,   // [B,T,2048] bf16 (bsum0 folded)
    const unsigned short* __restrict__ Whh0,  // [2048,512]
    const unsigned short* __restrict__ Wih1,  // [2048,512]
    const unsigned short* __restrict__ Whh1,  // [2048,512]
    const float* __restrict__ bsum1,          // [2048]
    unsigned short* __restrict__ hx1,         // [2][32*512]
    unsigned short* __restrict__ hx2,         // [2][32*512] (pre-zeroed)
    unsigned short* __restrict__ h2seq,       // [B,T,512]
    int* __restrict__ flags)                  // [96*32]
{
    __shared__ char smem[137856];
    int tid = threadIdx.x;
    int bid = blockIdx.x;
    int lane = tid & 63, wv = tid >> 6;
    int l15 = lane & 15, quad = lane >> 4;

    if (bid < 32) {
        // =================== L0: 16 dims, same structure as R8 ===================
        unsigned short* Ws   = (unsigned short*)smem;              // [64][520]
        unsigned short* hs   = Ws + 64 * 520;                      // [32][520]
        float*          gl   = (float*)(smem + 99840);             // [64][33]
        unsigned short* hout = (unsigned short*)(smem + 108288);   // [32][16]
        int d0 = bid * 16;
        {   // Whh0 slice: 64 rows x 512
            int r = tid >> 2, seg = tid & 3;
            int g = r >> 4, d = r & 15;
            const uint4* src = (const uint4*)(Whh0 + ((size_t)(g * 512 + d0 + d) * 512) + seg * 128);
            uint4* dst = (uint4*)(Ws + r * 520 + seg * 128);
            #pragma unroll
            for (int j = 0; j < 16; ++j) dst[j] = src[j];
        }
        int b_u = tid >> 3, dp = tid & 7;
        float c0r = 0.f, c1r = 0.f;
        __syncthreads();

        for (int i = 0; i <= 400; ++i) {
            if (i < 400) {
                int t = i;
                unsigned xv[4];
                {
                    const unsigned short* xr = xg0 + ((size_t)(b_u * T_ + t) * G4) + d0 + 2 * dp;
                    #pragma unroll
                    for (int g = 0; g < 4; ++g) xv[g] = *(const unsigned*)(xr + g * 512);
                }
                if (t > 0) {
                    const uint4* hrd = (const uint4*)(hx1 + ((t + 1) & 1) * (32 * 512));
                    #pragma unroll
                    for (int it = 0; it < 8; ++it) {
                        int u = it * 256 + tid;
                        int row = u >> 6, c8 = u & 63;
                        *(uint4*)(hs + row * 520 + c8 * 8) = hrd[u];
                    }
                    __syncthreads();
                    f32x4 acc0 = {}, acc1 = {};
                    #pragma unroll
                    for (int k0 = 0; k0 < 512; k0 += 32) {
                        s16x8 af = *(const s16x8*)(Ws + (wv * 16 + l15) * 520 + k0 + quad * 8);
                        s16x8 b0 = *(const s16x8*)(hs + l15 * 520 + k0 + quad * 8);
                        s16x8 b1 = *(const s16x8*)(hs + (16 + l15) * 520 + k0 + quad * 8);
                        acc0 = __builtin_amdgcn_mfma_f32_16x16x32_bf16(af, b0, acc0, 0, 0, 0);
                        acc1 = __builtin_amdgcn_mfma_f32_16x16x32_bf16(af, b1, acc1, 0, 0, 0);
                    }
                    #pragma unroll
                    for (int r = 0; r < 4; ++r) {
                        gl[(wv * 16 + quad * 4 + r) * 33 + l15]      = acc0[r];
                        gl[(wv * 16 + quad * 4 + r) * 33 + 16 + l15] = acc1[r];
                    }
                }
                __syncthreads();
                {
                    float h2v[2];
                    #pragma unroll
                    for (int q = 0; q < 2; ++q) {
                        int d = 2 * dp + q;
                        float iv = us2f((unsigned short)(xv[0] >> (16 * q)));
                        float fv = us2f((unsigned short)(xv[1] >> (16 * q)));
                        float gv = us2f((unsigned short)(xv[2] >> (16 * q)));
                        float ov = us2f((unsigned short)(xv[3] >> (16 * q)));
                        if (t > 0) {
                            iv += gl[(0 * 16 + d) * 33 + b_u];
                            fv += gl[(1 * 16 + d) * 33 + b_u];
                            gv += gl[(2 * 16 + d) * 33 + b_u];
                            ov += gl[(3 * 16 + d) * 33 + b_u];
                        }
                        float si = 1.f / (1.f + __expf(-iv));
                        float sf = 1.f / (1.f + __expf(-fv));
                        float so = 1.f / (1.f + __expf(-ov));
                        float tg = tanhf(gv);
                        float cold = (t > 0) ? (q ? c1r : c0r) : 0.f;
                        float c = sf * cold + si * tg;
                        float h = so * tanhf(c);
                        if (q) c1r = c; else c0r = c;
                        h2v[q] = h;
                    }
                    unsigned pk = (unsigned)f2bf(h2v[0]) | ((unsigned)f2bf(h2v[1]) << 16);
                    *(unsigned*)(hout + b_u * 16 + 2 * dp) = pk;
                }
                __syncthreads();
                if (tid < 64) {
                    int b = tid >> 1, hf = tid & 1;
                    uint4 v = *(const uint4*)(hout + b * 16 + hf * 8);
                    *(uint4*)(hx1 + (t & 1) * (32 * 512) + (size_t)b * 512 + d0 + hf * 8) = v;
                }
            }
            if (i < 400) {
                __syncthreads();
                if (tid == 0) {
                    __threadfence();
                    __hip_atomic_store(flags + bid * 32, i + 1, __ATOMIC_RELEASE, __HIP_MEMORY_SCOPE_AGENT);
                }
                if (tid < NB_) {
                    while (__hip_atomic_load(flags + tid * 32, __ATOMIC_RELAXED, __HIP_MEMORY_SCOPE_AGENT) < i + 1)
                        __builtin_amdgcn_s_sleep(1);
                }
                __syncthreads();
                if (tid == 0) __threadfence();
                __syncthreads();
            }
        }
    } else {
        // =================== L1: 8 dims, fused K=1024 matvec ===================
        unsigned short* Wc    = (unsigned short*)smem;             // [32][1040]
        unsigned short* hcat  = Wc + 32 * 1040;                    // [32][1040]
        float*          gl1   = (float*)(smem + 133120);           // [32][33]
        unsigned short* hout1 = (unsigned short*)(smem + 137344);  // [32][8]
        int bd1 = bid - 32;
        int d0 = bd1 * 8;
        {   // [W_ih1 | W_hh1] slice: 32 rows x 1024
            int r = tid >> 3, seg = tid & 7;
            int g = r >> 3, d = r & 7;
            const unsigned short* wsrc = ((seg < 4) ? Wih1 : Whh1)
                + (size_t)(g * 512 + d0 + d) * 512 + (seg & 3) * 128;
            uint4* wdst = (uint4*)(Wc + r * 1040 + seg * 128);
            const uint4* ws4 = (const uint4*)wsrc;
            #pragma unroll
            for (int j = 0; j < 16; ++j) wdst[j] = ws4[j];
        }
        int dd = tid >> 5, b_u = tid & 31;
        float bs[4];
        #pragma unroll
        for (int g = 0; g < 4; ++g) bs[g] = bsum1[g * 512 + d0 + dd];
        int mt = wv >> 1, nt = wv & 1;
        float creg = 0.f;
        __syncthreads();

        for (int i = 0; i <= 400; ++i) {
            if (i >= 1) {
                int t = i - 1;
                const uint4* s1 = (const uint4*)(hx1 + ((i - 1) & 1) * (32 * 512));
                const uint4* s2 = (const uint4*)(hx2 + ((i - 2) & 1) * (32 * 512));
                #pragma unroll
                for (int it = 0; it < 8; ++it) {
                    int u = it * 256 + tid;
                    int row = u >> 6, c8 = u & 63;
                    *(uint4*)(hcat + row * 1040 + c8 * 8)       = s1[u];
                    *(uint4*)(hcat + row * 1040 + 512 + c8 * 8) = s2[u];
                }
                __syncthreads();
                f32x4 acc = {};
                #pragma unroll 4
                for (int k0 = 0; k0 < 1024; k0 += 32) {
                    s16x8 af = *(const s16x8*)(Wc + (mt * 16 + l15) * 1040 + k0 + quad * 8);
                    s16x8 bf = *(const s16x8*)(hcat + (nt * 16 + l15) * 1040 + k0 + quad * 8);
                    acc = __builtin_amdgcn_mfma_f32_16x16x32_bf16(af, bf, acc, 0, 0, 0);
                }
                #pragma unroll
                for (int r = 0; r < 4; ++r)
                    gl1[(mt * 16 + quad * 4 + r) * 33 + nt * 16 + l15] = acc[r];
                __syncthreads();
                {
                    float iv = gl1[(0 * 8 + dd) * 33 + b_u] + bs[0];
                    float fv = gl1[(1 * 8 + dd) * 33 + b_u] + bs[1];
                    float gv = gl1[(2 * 8 + dd) * 33 + b_u] + bs[2];
                    float ov = gl1[(3 * 8 + dd) * 33 + b_u] + bs[3];
                    float si = 1.f / (1.f + __expf(-iv));
                    float sf = 1.f / (1.f + __expf(-fv));
                    float so = 1.f / (1.f + __expf(-ov));
                    float tg = tanhf(gv);
                    float cold = (t > 0) ? creg : 0.f;
                    float c = sf * cold + si * tg;
                    float h = so * tanhf(c);
                    creg = c;
                    hout1[b_u * 8 + dd] = f2bf(h);
                }
                __syncthreads();
                if (tid < 32) {
                    uint4 v = *(const uint4*)(hout1 + tid * 8);
                    *(uint4*)(hx2 + (t & 1) * (32 * 512) + (size_t)tid * 512 + d0) = v;
                    *(uint4*)(h2seq + ((size_t)tid * T_ + t) * 512 + d0) = v;
                }
            }
            if (i < 400) {
                __syncthreads();
                if (tid == 0) {
                    __threadfence();
                    __hip_atomic_store(flags + bid * 32, i + 1, __ATOMIC_RELEASE, __HIP_MEMORY_SCOPE_AGENT);
                }
                if (tid < NB_) {
                    while (__hip_atomic_load(flags + tid * 32, __ATOMIC_RELAXED, __HIP_MEMORY_SCOPE_AGENT) < i + 1)
                        __builtin_amdgcn_s_sleep(1);
                }
                __syncthreads();
                if (tid == 0) __threadfence();
                __syncthreads();
            }
        }
    }
}

// ---------------------------------------------------------------- stop head
__global__ __launch_bounds__(256) void k_stop(
    const unsigned short* __restrict__ h2, const float* __restrict__ W,
    const float* __restrict__ bsc, float* __restrict__ out)
{
    int w = threadIdx.x >> 6, lane = threadIdx.x & 63;
    int row = blockIdx.x * 4 + w;
    const unsigned short* hr = h2 + (size_t)row * 512 + lane * 8;
    float acc = 0.f;
    #pragma unroll
    for (int j = 0; j < 8; ++j) acc += us2f(hr[j]) * W[lane * 8 + j];
    #pragma unroll
    for (int off = 32; off; off >>= 1) acc += __shfl_xor(acc, off, 64);
    if (lane == 0) out[row] = acc + bsc[0];
}

// ---------------------------------------------------------------- BN stats (coalesced partial + atomic)
__global__ __launch_bounds__(256) void k_stats_part(
    const float* __restrict__ x, float* __restrict__ ssum, float* __restrict__ ssq)
{
    int r0 = blockIdx.x * 50;
    int c1 = threadIdx.x, c2 = threadIdx.x + 256;
    float s1 = 0.f, q1 = 0.f, s2 = 0.f, q2 = 0.f;
    for (int r = r0; r < r0 + 50; ++r) {
        float v1 = x[(size_t)r * 512 + c1]; s1 += v1; q1 += v1 * v1;
        float v2 = x[(size_t)r * 512 + c2]; s2 += v2; q2 += v2 * v2;
    }
    atomicAdd(&ssum[c1], s1); atomicAdd(&ssq[c1], q1);
    atomicAdd(&ssum[c2], s2); atomicAdd(&ssq[c2], q2);
}
__global__ __launch_bounds__(256) void k_stats_fin(
    float* __restrict__ ssum, float* __restrict__ ssq,
    const float* __restrict__ gw, const float* __restrict__ bw,
    float* __restrict__ scale, float* __restrict__ shift)
{
    int c = blockIdx.x * 256 + threadIdx.x;
    if (c < 512) {
        float mean = ssum[c] / (float)BT;
        float var  = ssq[c] / (float)BT - mean * mean;
        float scv  = gw[c] * rsqrtf(var + 1e-5f);
        scale[c] = scv;
        shift[c] = bw[c] - mean * scv;
        ssum[c] = 0.f; ssq[c] = 0.f;
    }
}

__global__ __launch_bounds__(256) void k_bnact(
    float* __restrict__ x, int C,
    const float* __restrict__ scale, const float* __restrict__ shift)
{
    int idx = blockIdx.x * 256 + threadIdx.x;
    if (idx < BT * C) {
        int c = idx % C;
        x[idx] = tanhf(scale[c] * x[idx] + shift[c]);
    }
}

__global__ __launch_bounds__(256) void k_residual(
    const float* __restrict__ mel, float* __restrict__ out)
{
    int i = blockIdx.x * 256 + threadIdx.x;
    if (i < BT * M_) out[i] += mel[i];
}

// ================================================================ launch
extern "C" void kernel_launch(void* const* d_in, const int* in_sizes, int n_in,
                              void* d_out, int out_size, void* d_ws, size_t ws_size,
                              hipStream_t stream)
{
    const float* enc    = (const float*)d_in[0];
    const float* mel_t  = (const float*)d_in[1];
    const float* W_in   = (const float*)d_in[2];
    const float* b_in   = (const float*)d_in[3];
    const float* Wq     = (const float*)d_in[4];  const float* bq = (const float*)d_in[5];
    const float* Wk     = (const float*)d_in[6];  const float* bk = (const float*)d_in[7];
    const float* Wv     = (const float*)d_in[8];  const float* bv = (const float*)d_in[9];
    const float* Wo     = (const float*)d_in[10]; const float* bo = (const float*)d_in[11];
    const float* W_ih0  = (const float*)d_in[12]; const float* W_hh0 = (const float*)d_in[13];
    const float* b_ih0  = (const float*)d_in[14]; const float* b_hh0 = (const float*)d_in[15];
    const float* W_ih1  = (const float*)d_in[16]; const float* W_hh1 = (const float*)d_in[17];
    const float* b_ih1  = (const float*)d_in[18]; const float* b_hh1 = (const float*)d_in[19];
    const float* W_mel  = (const float*)d_in[20]; const float* b_mel = (const float*)d_in[21];
    const float* W_stop = (const float*)d_in[22]; const float* b_stop = (const float*)d_in[23];
    const float* pw0 = (const float*)d_in[24]; const float* pb0 = (const float*)d_in[25];
    const float* pw1 = (const float*)d_in[26]; const float* pb1 = (const float*)d_in[27];
    const float* pw2 = (const float*)d_in[28]; const float* pb2 = (const float*)d_in[29];
    const float* pw3 = (const float*)d_in[30]; const float* pb3 = (const float*)d_in[31];
    const float* pw4 = (const float*)d_in[32]; const float* pb4 = (const float*)d_in[33];
    const float* g0 = (const float*)d_in[34]; const float* be0 = (const float*)d_in[35];
    const float* g1 = (const float*)d_in[36]; const float* be1 = (const float*)d_in[37];
    const float* g2 = (const float*)d_in[38]; const float* be2 = (const float*)d_in[39];
    const float* g3 = (const float*)d_in[40]; const float* be3 = (const float*)d_in[41];

    char* p = (char*)d_ws;
    // early: Kb[0,16.8M) Vb[16.8,33.6M) ctx[33.6,59.8M); ao[0,26.2M) after attn;
    // xg0 bf16 [26.2,78.6M) after ao (ctx dead); LSTM writes h2seq[0,13.1M) (ao dead);
    // postnet: p_a[13.1,39.3M), p_b[39.3,65.5M) (xg0 dead after LSTM).
    float* Kb  = (float*)(p + 0);
    float* Vb  = (float*)(p + 16777216);
    float* ctx = (float*)(p + 33554432);
    float* ao  = (float*)(p + 0);
    unsigned short* xg0   = (unsigned short*)(p + 26214400);
    unsigned short* h2seq = (unsigned short*)(p + 0);
    float* p_a = (float*)(p + 13107200);
    float* p_b = (float*)(p + 39321600);
    size_t off = 78643200;
    float* bsum0 = (float*)(p + off); off += 8192;
    float* bsum1 = (float*)(p + off); off += 8192;
    unsigned short* hx1 = (unsigned short*)(p + off); off += 65536;
    unsigned short* hx2 = (unsigned short*)(p + off); off += 65536;
    int* flags = (int*)(p + off); off += 12288;
    float* beff = (float*)(p + off); off += 2048;
    float* Weff = (float*)(p + off); off += 163840;
    float* sc0 = (float*)(p + off); off += 2048;
    float* sh0 = (float*)(p + off); off += 2048;
    float* sc1 = (float*)(p + off); off += 2048;
    float* sh1 = (float*)(p + off); off += 2048;
    float* sc2 = (float*)(p + off); off += 2048;
    float* sh2 = (float*)(p + off); off += 2048;
    float* sc3 = (float*)(p + off); off += 2048;
    float* sh3 = (float*)(p + off); off += 2048;
    float* ssum = (float*)(p + off); off += 2048;
    float* ssq  = (float*)(p + off); off += 2048;
    unsigned short* Wk_t   = (unsigned short*)(p + off); off += 524288;
    unsigned short* Wv_t   = (unsigned short*)(p + off); off += 524288;
    unsigned short* Wo_t   = (unsigned short*)(p + off); off += 524288;
    unsigned short* Wmel_t = (unsigned short*)(p + off); off += 81920;
    unsigned short* Wih0_b = (unsigned short*)(p + off); off += 2424832;
    unsigned short* Wih1_b = (unsigned short*)(p + off); off += 2097152;
    unsigned short* Whh0_b = (unsigned short*)(p + off); off += 2097152;
    unsigned short* Whh1_b = (unsigned short*)(p + off); off += 2097152;
    unsigned short* pw0_b  = (unsigned short*)(p + off); off += 409600;
    unsigned short* pw1_b  = (unsigned short*)(p + off); off += 2621440;
    unsigned short* pw2_b  = (unsigned short*)(p + off); off += 2621440;
    unsigned short* pw3_b  = (unsigned short*)(p + off); off += 2621440;
    unsigned short* pw4_b  = (unsigned short*)(p + off); off += 409600;

    float* out_mel  = (float*)d_out;
    float* out_post = out_mel + (size_t)BT * M_;
    float* out_stop = out_post + (size_t)BT * M_;

    dim3 blk(256);
    auto MF = [&](const void* A, int lda, const float* mel, int srcC,
                  const unsigned short* Bt, void* C, int ldc, const float* bias,
                  int M, int N, int K, int mode, int abf16, int cbf16) {
        dim3 g((M + 127) / 128, (N + 127) / 128);
        k_mfma<<<g, blk, 0, stream>>>(A, lda, mel, srcC, Bt, C, ldc, bias, M, N, K, mode, abf16, cbf16);
    };

    // ---- prep (batched)
    k_prep<<<128, blk, 0, stream>>>(b_ih0, b_hh0, b_ih1, b_hh1, bsum0, bsum1,
                                    flags, (int*)hx2, ssum, ssq);
    k_weff<<<160, blk, 0, stream>>>(W_in, Wq, b_in, bq, Weff, beff);
    {
        dim3 gc(4736, 4);
        k_w_c4<<<gc, blk, 0, stream>>>(W_ih0, Wih0_b, G4 * DM,
                                       W_ih1, Wih1_b, G4 * D_,
                                       W_hh0, Whh0_b, G4 * D_,
                                       W_hh1, Whh1_b, G4 * D_);
        dim3 gt(1024, 4);
        k_w_t4<<<gt, blk, 0, stream>>>(Wk, Wk_t, D_, D_,
                                       Wv, Wv_t, D_, D_,
                                       Wo, Wo_t, D_, D_,
                                       W_mel, Wmel_t, D_, M_);
        dim3 gv(5120, 5);
        k_w_conv5<<<gv, blk, 0, stream>>>(pw0, pw0_b, 512, 80,
                                          pw1, pw1_b, 512, 512,
                                          pw2, pw2_b, 512, 512,
                                          pw3, pw3_b, 512, 512,
                                          pw4, pw4_b, 80, 512);
    }

    // ---- K/V projections
    MF(enc, D_, nullptr, 0, Wk_t, Kb, D_, bk, BS, D_, D_, 0, 0, 0);
    MF(enc, D_, nullptr, 0, Wv_t, Vb, D_, bv, BS, D_, D_, 0, 0, 0);

    // ---- attention
    k_attn<<<(B_ * H_ * T_) / 4, blk, 0, stream>>>(mel_t, Weff, beff, Kb, Vb, ctx);

    // ---- attn_out = ctx @ Wo + bo
    MF(ctx, D_, nullptr, 0, Wo_t, ao, D_, bo, BT, D_, D_, 0, 0, 0);

    // ---- xg0 (full T, bf16 out, virtual [ao | dec_in] concat, K=592)
    MF(ao, D_, mel_t, 0, Wih0_b, xg0, G4, bsum0, BT, G4, DM, 1, 0, 1);

    // ---- fused pipelined 2-layer LSTM (single launch)
    k_lstm2<<<NB_, blk, 0, stream>>>(xg0, Whh0_b, Wih1_b, Whh1_b, bsum1,
                                     hx1, hx2, h2seq, flags);

    // ---- heads
    MF(h2seq, D_, nullptr, 0, Wmel_t, out_mel, M_, b_mel, BT, M_, D_, 0, 1, 0);
    k_stop<<<BT / 4, blk, 0, stream>>>(h2seq, W_stop, b_stop, out_stop);

    // ---- postnet (conv weights permuted to (tap-major, channel-minor))
    int gD = (BT * D_ + 255) / 256;

    MF(out_mel, 0, nullptr, M_, pw0_b, p_a, D_, pb0, BT, D_, M_ * 5, 2, 0, 0);
    k_stats_part<<<256, blk, 0, stream>>>(p_a, ssum, ssq);
    k_stats_fin<<<2, blk, 0, stream>>>(ssum, ssq, g0, be0, sc0, sh0);
    k_bnact<<<gD, blk, 0, stream>>>(p_a, D_, sc0, sh0);

    MF(p_a, 0, nullptr, D_, pw1_b, p_b, D_, pb1, BT, D_, D_ * 5, 2, 0, 0);
    k_stats_part<<<256, blk, 0, stream>>>(p_b, ssum, ssq);
    k_stats_fin<<<2, blk, 0, stream>>>(ssum, ssq, g1, be1, sc1, sh1);
    k_bnact<<<gD, blk, 0, stream>>>(p_b, D_, sc1, sh1);

    MF(p_b, 0, nullptr, D_, pw2_b, p_a, D_, pb2, BT, D_, D_ * 5, 2, 0, 0);
    k_stats_part<<<256, blk, 0, stream>>>(p_a, ssum, ssq);
    k_stats_fin<<<2, blk, 0, stream>>>(ssum, ssq, g2, be2, sc2, sh2);
    k_bnact<<<gD, blk, 0, stream>>>(p_a, D_, sc2, sh2);

    MF(p_a, 0, nullptr, D_, pw3_b, p_b, D_, pb3, BT, D_, D_ * 5, 2, 0, 0);
    k_stats_part<<<256, blk, 0, stream>>>(p_b, ssum, ssq);
    k_stats_fin<<<2, blk, 0, stream>>>(ssum, ssq, g3, be3, sc3, sh3);
    k_bnact<<<gD, blk, 0, stream>>>(p_b, D_, sc3, sh3);

    MF(p_b, 0, nullptr, D_, pw4_b, out_post, M_, pb4, BT, M_, D_ * 5, 2, 0, 0);
    k_residual<<<4000, blk, 0, stream>>>(out_mel, out_post);
}